// Round 4
// baseline (902.704 us; speedup 1.0000x reference)
//
#include <hip/hip_runtime.h>
#include <hip/hip_bf16.h>
#include <math.h>
#include <stdint.h>

#define DIM 1024
#define FF 4096
#define NE 8
#define NTOK 8192
#define NASSIGN (NTOK * 2)
#define MB_MAX (NTOK / 256)     // 32 max m-blocks per expert

typedef short short8 __attribute__((ext_vector_type(8)));
typedef float f32x4 __attribute__((ext_vector_type(4)));

static __device__ __forceinline__ short bf16_of(float f) {
    union { float f; unsigned u; } v; v.f = f;
    unsigned r = v.u + 0x7fffu + ((v.u >> 16) & 1u);   // RNE
    return (short)(r >> 16);
}

static __device__ __forceinline__ short8 cvt8(float4 a, float4 b) {
    short8 r;
    r[0] = bf16_of(a.x); r[1] = bf16_of(a.y); r[2] = bf16_of(a.z); r[3] = bf16_of(a.w);
    r[4] = bf16_of(b.x); r[5] = bf16_of(b.y); r[6] = bf16_of(b.z); r[7] = bf16_of(b.w);
    return r;
}

static __device__ __forceinline__ void gl_lds16(const short* g, short* lds) {
    __builtin_amdgcn_global_load_lds(
        (const __attribute__((address_space(1))) void*)g,
        (__attribute__((address_space(3))) void*)lds, 16, 0, 0);
}

// ---------------- f32 -> bf16 bulk convert ----------------
__global__ __launch_bounds__(256) void cvt_k(const float* __restrict__ in,
                                             short* __restrict__ out, int n8) {
    int i = blockIdx.x * blockDim.x + threadIdx.x;
    if (i >= n8) return;
    float4 a = ((const float4*)in)[2 * i];
    float4 b = ((const float4*)in)[2 * i + 1];
    ((short8*)out)[i] = cvt8(a, b);
}

// ---------------- router ----------------
__global__ void router_k(const float* __restrict__ x, const float* __restrict__ Wr,
                         int* __restrict__ cnt, int* __restrict__ a_exp,
                         int* __restrict__ a_pos, float* __restrict__ a_w) {
    int t = blockIdx.x;
    int lane = threadIdx.x;
    const float* xr = x + (size_t)t * DIM;
    float p[NE];
#pragma unroll
    for (int e = 0; e < NE; ++e) p[e] = 0.f;
    for (int i = 0; i < DIM / 64; ++i) {
        float xv = xr[lane + i * 64];
#pragma unroll
        for (int e = 0; e < NE; ++e) p[e] += xv * Wr[e * DIM + lane + i * 64];
    }
#pragma unroll
    for (int off = 32; off >= 1; off >>= 1)
#pragma unroll
        for (int e = 0; e < NE; ++e) p[e] += __shfl_xor(p[e], off);
    if (lane == 0) {
        float mx = p[0];
#pragma unroll
        for (int e = 1; e < NE; ++e) mx = fmaxf(mx, p[e]);
        float pr[NE]; float s = 0.f;
#pragma unroll
        for (int e = 0; e < NE; ++e) { pr[e] = expf(p[e] - mx); s += pr[e]; }
#pragma unroll
        for (int e = 0; e < NE; ++e) pr[e] /= s;
        int i1 = 0;
#pragma unroll
        for (int e = 1; e < NE; ++e) if (pr[e] > pr[i1]) i1 = e;
        int i2 = (i1 == 0) ? 1 : 0;
#pragma unroll
        for (int e = 0; e < NE; ++e) if (e != i1 && pr[e] > pr[i2]) i2 = e;
        float w1 = pr[i1], w2 = pr[i2], nrm = w1 + w2;
        w1 /= nrm; w2 /= nrm;
        int p1 = atomicAdd(&cnt[i1], 1);
        int p2 = atomicAdd(&cnt[i2], 1);
        a_exp[2 * t] = i1;     a_pos[2 * t] = p1;     a_w[2 * t] = w1;
        a_exp[2 * t + 1] = i2; a_pos[2 * t + 1] = p2; a_w[2 * t + 1] = w2;
    }
}

__global__ void offsets_k(const int* __restrict__ cnt, int* __restrict__ offs) {
    if (threadIdx.x == 0) {
        int s = 0;
        for (int e = 0; e < NE; ++e) { offs[e] = s; s += cnt[e]; }
        offs[NE] = s;
    }
}

__global__ void scatter_k(const int* __restrict__ a_exp, const int* __restrict__ a_pos,
                          const float* __restrict__ a_w, const int* __restrict__ offs,
                          int* __restrict__ ptok, float* __restrict__ pw,
                          int* __restrict__ slot_of) {
    int a = blockIdx.x * blockDim.x + threadIdx.x;
    if (a >= NASSIGN) return;
    int e = a_exp[a];
    int r = offs[e] + a_pos[a];
    ptok[r] = a >> 1;
    pw[r] = a_w[a];
    slot_of[a] = r;
}

// ------------- 256x256 grouped GEMM core, BK=32, dbuf LDS, counted vmcnt -------------
// C[256x256] = A[256 x KDIM] * B[256 x KDIM]^T, bf16, K-contiguous rows.
// 512 threads = 8 waves (2 M x 4 N); per-wave output 128x64; acc[8][4] of 16x16 frags.
template <int KDIM, bool GATHER>
__device__ __forceinline__ void gemm_core256(const short* __restrict__ A,
                                             const int* __restrict__ ptok,
                                             const short* __restrict__ B,
                                             int offs_e, int cnt_e, int m0, int n0,
                                             f32x4 acc[8][4],
                                             short* As, short* Bs) {
    const int tid = threadIdx.x;
    const int lane = tid & 63, wave = tid >> 6;
    const int wr = wave >> 2, wc = wave & 3;

#pragma unroll
    for (int m = 0; m < 8; ++m)
#pragma unroll
        for (int n = 0; n < 4; ++n) acc[m][n] = (f32x4){0.f, 0.f, 0.f, 0.f};

    // staging: thread tid covers rows srow and srow+128, col-quad kq (8 bf16 = 16B)
    const int srow = tid >> 2, kq = tid & 3;
    int gm0 = m0 + srow;       if (gm0 >= cnt_e) gm0 = cnt_e - 1;
    int gm1 = m0 + srow + 128; if (gm1 >= cnt_e) gm1 = cnt_e - 1;
    const short* aptr0 = A + (GATHER ? (size_t)ptok[offs_e + gm0]
                                     : (size_t)(offs_e + gm0)) * KDIM + kq * 8;
    const short* aptr1 = A + (GATHER ? (size_t)ptok[offs_e + gm1]
                                     : (size_t)(offs_e + gm1)) * KDIM + kq * 8;
    const short* bptr0 = B + (size_t)(n0 + srow) * KDIM + kq * 8;
    const short* bptr1 = B + (size_t)(n0 + srow + 128) * KDIM + kq * 8;

    auto stage = [&](int bufsel, int ktile) {
        const int o = bufsel * 8192;           // buffer stride in shorts (256*32)
        gl_lds16(aptr0 + ktile * 32, As + o + tid * 8);
        gl_lds16(aptr1 + ktile * 32, As + o + 4096 + tid * 8);
        gl_lds16(bptr0 + ktile * 32, Bs + o + tid * 8);
        gl_lds16(bptr1 + ktile * 32, Bs + o + 4096 + tid * 8);
    };

    const int fr = lane & 15, koff = (lane >> 4) * 8;   // shorts
    const int NK = KDIM / 32;

    stage(0, 0);   // prologue

    for (int kt = 0; kt < NK; ++kt) {
        const int cur = kt & 1;
        if (kt + 1 < NK) {
            stage(cur ^ 1, kt + 1);                       // next tile -> other buffer
            asm volatile("s_waitcnt vmcnt(4)" ::: "memory");  // current tile landed
        } else {
            asm volatile("s_waitcnt vmcnt(0)" ::: "memory");
        }
        __builtin_amdgcn_sched_barrier(0);
        __builtin_amdgcn_s_barrier();                     // all waves: tile kt resident

        const short* Ab = As + cur * 8192;
        const short* Bb = Bs + cur * 8192;
        short8 bfrag[4], afrag[4];
#pragma unroll
        for (int n = 0; n < 4; ++n)
            bfrag[n] = *(const short8*)&Bb[(wc * 64 + n * 16 + fr) * 32 + koff];
#pragma unroll
        for (int m = 0; m < 4; ++m)
            afrag[m] = *(const short8*)&Ab[(wr * 128 + m * 16 + fr) * 32 + koff];
        __builtin_amdgcn_s_setprio(1);
#pragma unroll
        for (int m = 0; m < 4; ++m)
#pragma unroll
            for (int n = 0; n < 4; ++n)
                acc[m][n] = __builtin_amdgcn_mfma_f32_16x16x32_bf16(afrag[m], bfrag[n], acc[m][n], 0, 0, 0);
        __builtin_amdgcn_s_setprio(0);
#pragma unroll
        for (int m = 0; m < 4; ++m)
            afrag[m] = *(const short8*)&Ab[(wr * 128 + 64 + m * 16 + fr) * 32 + koff];
        __builtin_amdgcn_s_setprio(1);
#pragma unroll
        for (int m = 0; m < 4; ++m)
#pragma unroll
            for (int n = 0; n < 4; ++n)
                acc[4 + m][n] = __builtin_amdgcn_mfma_f32_16x16x32_bf16(afrag[m], bfrag[n], acc[4 + m][n], 0, 0, 0);
        __builtin_amdgcn_s_setprio(0);
        __builtin_amdgcn_s_barrier();   // all reads of buf[cur] done; next iter overwrites it
    }
}

// ---------------- GEMM1: H = gelu(Xg @ W1[e]^T + b1[e]) ----------------
#define G1_NX (FF / 256)                 // 16
#define G1_NWG (G1_NX * MB_MAX * NE)     // 4096
__global__ __launch_bounds__(512, 2) void gemm1_k(const short* __restrict__ xb,
                                                  const short* __restrict__ W1b,
                                                  const float* __restrict__ b1,
                                                  const int* __restrict__ cnt,
                                                  const int* __restrict__ offs,
                                                  const int* __restrict__ ptok,
                                                  short* __restrict__ H) {
    __shared__ __align__(16) short As[2 * 8192];
    __shared__ __align__(16) short Bs[2 * 8192];
    int wg = (blockIdx.x % 8) * (G1_NWG / 8) + blockIdx.x / 8;   // XCD swizzle (bijective)
    const int n0 = (wg % G1_NX) * 256;  wg /= G1_NX;
    const int m0 = (wg % MB_MAX) * 256; wg /= MB_MAX;
    const int e = wg;
    const int cnt_e = cnt[e], offs_e = offs[e];
    if (m0 >= cnt_e) return;

    f32x4 acc[8][4];
    gemm_core256<DIM, true>(xb, ptok, W1b + (size_t)e * FF * DIM, offs_e, cnt_e, m0, n0, acc, As, Bs);

    const int lane = threadIdx.x & 63, wave = threadIdx.x >> 6;
    const int wr = wave >> 2, wc = wave & 3;
    const int colb = lane & 15, rowb = (lane >> 4) * 4;
    float b1v[4];
#pragma unroll
    for (int n = 0; n < 4; ++n) b1v[n] = b1[e * FF + n0 + wc * 64 + n * 16 + colb];
#pragma unroll
    for (int m = 0; m < 8; ++m) {
#pragma unroll
        for (int r = 0; r < 4; ++r) {
            const int gm = m0 + wr * 128 + m * 16 + rowb + r;
            if (gm >= cnt_e) continue;
#pragma unroll
            for (int n = 0; n < 4; ++n) {
                const int col = n0 + wc * 64 + n * 16 + colb;
                float v = acc[m][n][r] + b1v[n];
                v = 0.5f * v * (1.f + erff(v * 0.70710678118f));
                H[(size_t)(offs_e + gm) * FF + col] = bf16_of(v);
            }
        }
    }
}

// ---------------- GEMM2: y[slot] = H @ W2[e]^T + b2[e] ----------------
#define G2_NX (DIM / 256)                // 4
#define G2_NWG (G2_NX * MB_MAX * NE)     // 1024
__global__ __launch_bounds__(512, 2) void gemm2_k(const short* __restrict__ H,
                                                  const short* __restrict__ W2b,
                                                  const float* __restrict__ b2,
                                                  const int* __restrict__ cnt,
                                                  const int* __restrict__ offs,
                                                  float* __restrict__ y) {
    __shared__ __align__(16) short As[2 * 8192];
    __shared__ __align__(16) short Bs[2 * 8192];
    int wg = (blockIdx.x % 8) * (G2_NWG / 8) + blockIdx.x / 8;
    const int n0 = (wg % G2_NX) * 256;  wg /= G2_NX;
    const int m0 = (wg % MB_MAX) * 256; wg /= MB_MAX;
    const int e = wg;
    const int cnt_e = cnt[e], offs_e = offs[e];
    if (m0 >= cnt_e) return;

    f32x4 acc[8][4];
    gemm_core256<FF, false>(H, nullptr, W2b + (size_t)e * DIM * FF, offs_e, cnt_e, m0, n0, acc, As, Bs);

    const int lane = threadIdx.x & 63, wave = threadIdx.x >> 6;
    const int wr = wave >> 2, wc = wave & 3;
    const int colb = lane & 15, rowb = (lane >> 4) * 4;
    float b2v[4];
#pragma unroll
    for (int n = 0; n < 4; ++n) b2v[n] = b2[e * DIM + n0 + wc * 64 + n * 16 + colb];
#pragma unroll
    for (int m = 0; m < 8; ++m) {
#pragma unroll
        for (int r = 0; r < 4; ++r) {
            const int gm = m0 + wr * 128 + m * 16 + rowb + r;
            if (gm >= cnt_e) continue;
#pragma unroll
            for (int n = 0; n < 4; ++n) {
                const int col = n0 + wc * 64 + n * 16 + colb;
                y[(size_t)(offs_e + gm) * DIM + col] = acc[m][n][r] + b2v[n];
            }
        }
    }
}

// ---------------- combine: out[t] = w1*y[s1] + w2*y[s2] ----------------
__global__ __launch_bounds__(256) void combine_k(const float* __restrict__ y,
                                                 const int* __restrict__ slot_of,
                                                 const float* __restrict__ a_w,
                                                 float* __restrict__ out) {
    const int t = blockIdx.x;
    const int c = threadIdx.x;
    const int s1 = slot_of[2 * t], s2 = slot_of[2 * t + 1];
    const float w1 = a_w[2 * t], w2 = a_w[2 * t + 1];
    float4 v1 = ((const float4*)(y + (size_t)s1 * DIM))[c];
    float4 v2 = ((const float4*)(y + (size_t)s2 * DIM))[c];
    float4 o;
    o.x = w1 * v1.x + w2 * v2.x;
    o.y = w1 * v1.y + w2 * v2.y;
    o.z = w1 * v1.z + w2 * v2.z;
    o.w = w1 * v1.w + w2 * v2.w;
    ((float4*)(out + (size_t)t * DIM))[c] = o;
}

// ---------------- launch ----------------
extern "C" void kernel_launch(void* const* d_in, const int* in_sizes, int n_in,
                              void* d_out, int out_size, void* d_ws, size_t ws_size,
                              hipStream_t stream) {
    const float* x  = (const float*)d_in[0];
    const float* Wr = (const float*)d_in[1];
    const float* W1 = (const float*)d_in[2];
    const float* b1 = (const float*)d_in[3];
    const float* W2 = (const float*)d_in[4];
    const float* b2 = (const float*)d_in[5];
    float* out = (float*)d_out;

    char* w = (char*)d_ws;
    int*   cnt     = (int*)w;
    int*   offs    = (int*)(w + 64);
    int*   a_exp   = (int*)(w + 128);
    int*   a_pos   = a_exp + NASSIGN;
    int*   ptok    = a_pos + NASSIGN;
    int*   slot_of = ptok + NASSIGN;
    float* a_w     = (float*)(slot_of + NASSIGN);
    float* pw      = a_w + NASSIGN;
    char*  p       = (char*)(pw + NASSIGN);
    p = (char*)(((uintptr_t)p + 255) & ~(uintptr_t)255);
    short* xb  = (short*)p;                p += (size_t)NTOK * DIM * 2;
    short* W1b = (short*)p;                p += (size_t)NE * FF * DIM * 2;
    short* W2b = (short*)p;                p += (size_t)NE * DIM * FF * 2;
    short* H   = (short*)p;                // NASSIGN * FF * 2 = 134 MB
    // y aliases W1b (dead after gemm1); NASSIGN*DIM*4 == NE*FF*DIM*2
    float* y   = (float*)W1b;

    hipMemsetAsync(cnt, 0, 32, stream);

    cvt_k<<<(NTOK * DIM / 8 + 255) / 256, 256, 0, stream>>>(x, xb, NTOK * DIM / 8);
    cvt_k<<<(NE * FF * DIM / 8 + 255) / 256, 256, 0, stream>>>(W1, W1b, NE * FF * DIM / 8);
    cvt_k<<<(NE * DIM * FF / 8 + 255) / 256, 256, 0, stream>>>(W2, W2b, NE * DIM * FF / 8);

    router_k<<<NTOK, 64, 0, stream>>>(x, Wr, cnt, a_exp, a_pos, a_w);
    offsets_k<<<1, 64, 0, stream>>>(cnt, offs);
    scatter_k<<<NASSIGN / 256, 256, 0, stream>>>(a_exp, a_pos, a_w, offs, ptok, pw, slot_of);

    gemm1_k<<<G1_NWG, 512, 0, stream>>>(xb, W1b, b1, cnt, offs, ptok, H);
    gemm2_k<<<G2_NWG, 512, 0, stream>>>(H, W2b, b2, cnt, offs, y);
    combine_k<<<NTOK, 256, 0, stream>>>(y, slot_of, a_w, out);
}

// Round 5
// 870.902 us; speedup vs baseline: 1.0365x; 1.0365x over previous
//
#include <hip/hip_runtime.h>
#include <hip/hip_bf16.h>
#include <math.h>
#include <stdint.h>

#define DIM 1024
#define FF 4096
#define NE 8
#define NTOK 8192
#define NASSIGN (NTOK * 2)
#define MB_MAX (NTOK / 256)     // 32 max m-blocks per expert

typedef short short8 __attribute__((ext_vector_type(8)));
typedef float f32x4 __attribute__((ext_vector_type(4)));

static __device__ __forceinline__ short bf16_of(float f) {
    union { float f; unsigned u; } v; v.f = f;
    unsigned r = v.u + 0x7fffu + ((v.u >> 16) & 1u);   // RNE
    return (short)(r >> 16);
}

static __device__ __forceinline__ short8 cvt8(float4 a, float4 b) {
    short8 r;
    r[0] = bf16_of(a.x); r[1] = bf16_of(a.y); r[2] = bf16_of(a.z); r[3] = bf16_of(a.w);
    r[4] = bf16_of(b.x); r[5] = bf16_of(b.y); r[6] = bf16_of(b.z); r[7] = bf16_of(b.w);
    return r;
}

static __device__ __forceinline__ void gl_lds16(const short* g, short* lds) {
    __builtin_amdgcn_global_load_lds(
        (const __attribute__((address_space(1))) void*)g,
        (__attribute__((address_space(3))) void*)lds, 16, 0, 0);
}

// ---------------- f32 -> bf16 bulk convert ----------------
__global__ __launch_bounds__(256) void cvt_k(const float* __restrict__ in,
                                             short* __restrict__ out, int n8) {
    int i = blockIdx.x * blockDim.x + threadIdx.x;
    if (i >= n8) return;
    float4 a = ((const float4*)in)[2 * i];
    float4 b = ((const float4*)in)[2 * i + 1];
    ((short8*)out)[i] = cvt8(a, b);
}

// ---------------- router ----------------
__global__ void router_k(const float* __restrict__ x, const float* __restrict__ Wr,
                         int* __restrict__ cnt, int* __restrict__ a_exp,
                         int* __restrict__ a_pos, float* __restrict__ a_w) {
    int t = blockIdx.x;
    int lane = threadIdx.x;
    const float* xr = x + (size_t)t * DIM;
    float p[NE];
#pragma unroll
    for (int e = 0; e < NE; ++e) p[e] = 0.f;
    for (int i = 0; i < DIM / 64; ++i) {
        float xv = xr[lane + i * 64];
#pragma unroll
        for (int e = 0; e < NE; ++e) p[e] += xv * Wr[e * DIM + lane + i * 64];
    }
#pragma unroll
    for (int off = 32; off >= 1; off >>= 1)
#pragma unroll
        for (int e = 0; e < NE; ++e) p[e] += __shfl_xor(p[e], off);
    if (lane == 0) {
        float mx = p[0];
#pragma unroll
        for (int e = 1; e < NE; ++e) mx = fmaxf(mx, p[e]);
        float pr[NE]; float s = 0.f;
#pragma unroll
        for (int e = 0; e < NE; ++e) { pr[e] = expf(p[e] - mx); s += pr[e]; }
#pragma unroll
        for (int e = 0; e < NE; ++e) pr[e] /= s;
        int i1 = 0;
#pragma unroll
        for (int e = 1; e < NE; ++e) if (pr[e] > pr[i1]) i1 = e;
        int i2 = (i1 == 0) ? 1 : 0;
#pragma unroll
        for (int e = 0; e < NE; ++e) if (e != i1 && pr[e] > pr[i2]) i2 = e;
        float w1 = pr[i1], w2 = pr[i2], nrm = w1 + w2;
        w1 /= nrm; w2 /= nrm;
        int p1 = atomicAdd(&cnt[i1], 1);
        int p2 = atomicAdd(&cnt[i2], 1);
        a_exp[2 * t] = i1;     a_pos[2 * t] = p1;     a_w[2 * t] = w1;
        a_exp[2 * t + 1] = i2; a_pos[2 * t + 1] = p2; a_w[2 * t + 1] = w2;
    }
}

__global__ void offsets_k(const int* __restrict__ cnt, int* __restrict__ offs) {
    if (threadIdx.x == 0) {
        int s = 0;
        for (int e = 0; e < NE; ++e) { offs[e] = s; s += cnt[e]; }
        offs[NE] = s;
    }
}

__global__ void scatter_k(const int* __restrict__ a_exp, const int* __restrict__ a_pos,
                          const float* __restrict__ a_w, const int* __restrict__ offs,
                          int* __restrict__ ptok, float* __restrict__ pw,
                          int* __restrict__ slot_of) {
    int a = blockIdx.x * blockDim.x + threadIdx.x;
    if (a >= NASSIGN) return;
    int e = a_exp[a];
    int r = offs[e] + a_pos[a];
    ptok[r] = a >> 1;
    pw[r] = a_w[a];
    slot_of[a] = r;
}

// ============ 256x256 grouped GEMM core, BK=64, 4-phase pipelined schedule ============
// LDS: 2 K-tile buffers (A 256x64, B 256x64 bf16 each) = 128 KB. 8 waves (2M x 4N).
// Swizzle: LDS[row][slot] holds global[row][slot ^ (row&7)]  (slot = 16B chunk, 8/row).
// Per K-tile t: p0 {vmcnt(0); barrier; stage ALL of kt t+1; read A-mh0 + B-n01; MFMA}
//               p1 {read B-n23; MFMA}  p2 {read A-mh1; MFMA}  p3 {MFMA}  (barrier each)
// Safety: stage targets buf last read at kt t-1 (sealed by p0 barrier); reads of each
// phase drained by its lgkmcnt(0) before the next barrier.
#define MFMA_BF16 __builtin_amdgcn_mfma_f32_16x16x32_bf16

template <int KDIM, bool GATHER>
__device__ __forceinline__ void gemm_core256(const short* __restrict__ A,
                                             const int* __restrict__ ptok,
                                             const short* __restrict__ B,
                                             int offs_e, int cnt_e, int m0, int n0,
                                             f32x4 acc[8][4],
                                             short (*As)[16384], short (*Bs)[16384]) {
    const int tid = threadIdx.x;
    const int lane = tid & 63, wave = tid >> 6;
    const int wr = wave >> 2, wc = wave & 3;

#pragma unroll
    for (int m = 0; m < 8; ++m)
#pragma unroll
        for (int n = 0; n < 4; ++n) acc[m][n] = (f32x4){0.f, 0.f, 0.f, 0.f};

    // ---- staging setup: thread covers rows srow+{0,64,128,192}, 16B slot sslot ----
    const int srow = tid >> 3, sslot = tid & 7;
    const int gslot = sslot ^ (srow & 7);          // inverse-swizzled global slot
    int r0 = m0 + srow;       if (r0 >= cnt_e) r0 = cnt_e - 1;
    int r1 = m0 + srow + 64;  if (r1 >= cnt_e) r1 = cnt_e - 1;
    int r2 = m0 + srow + 128; if (r2 >= cnt_e) r2 = cnt_e - 1;
    int r3 = m0 + srow + 192; if (r3 >= cnt_e) r3 = cnt_e - 1;
    const short* aP0 = A + (GATHER ? (size_t)ptok[offs_e + r0] : (size_t)(offs_e + r0)) * KDIM + gslot * 8;
    const short* aP1 = A + (GATHER ? (size_t)ptok[offs_e + r1] : (size_t)(offs_e + r1)) * KDIM + gslot * 8;
    const short* aP2 = A + (GATHER ? (size_t)ptok[offs_e + r2] : (size_t)(offs_e + r2)) * KDIM + gslot * 8;
    const short* aP3 = A + (GATHER ? (size_t)ptok[offs_e + r3] : (size_t)(offs_e + r3)) * KDIM + gslot * 8;
    const short* bP0 = B + (size_t)(n0 + srow) * KDIM + gslot * 8;

    auto stage = [&](int nxt, int t) {
        const int co = t * 64;                     // shorts
        gl_lds16(aP0 + co, &As[nxt][(0 * 512 + tid) * 8]);
        gl_lds16(aP1 + co, &As[nxt][(1 * 512 + tid) * 8]);
        gl_lds16(aP2 + co, &As[nxt][(2 * 512 + tid) * 8]);
        gl_lds16(aP3 + co, &As[nxt][(3 * 512 + tid) * 8]);
        gl_lds16(bP0 + co,                      &Bs[nxt][(0 * 512 + tid) * 8]);
        gl_lds16(bP0 + (size_t)64  * KDIM + co, &Bs[nxt][(1 * 512 + tid) * 8]);
        gl_lds16(bP0 + (size_t)128 * KDIM + co, &Bs[nxt][(2 * 512 + tid) * 8]);
        gl_lds16(bP0 + (size_t)192 * KDIM + co, &Bs[nxt][(3 * 512 + tid) * 8]);
    };

    const int fr = lane & 15, sw = fr & 7, g4 = lane >> 4;
    const int NK = KDIM / 64;

    stage(0, 0);   // prologue

    short8 aF[2][4], bF[2][4];   // all indices compile-time (rule #20)

    for (int t = 0; t < NK; ++t) {
        const int cur = t & 1;
        asm volatile("s_waitcnt vmcnt(0)" ::: "memory");
        __builtin_amdgcn_sched_barrier(0);
        __builtin_amdgcn_s_barrier();              // kt t fully resident, buf cur^1 free
        __builtin_amdgcn_sched_barrier(0);
        if (t + 1 < NK) stage(cur ^ 1, t + 1);     // all 8 prefetch loads, 4 phases of cover
        const short* Ab = As[cur];
        const short* Bb = Bs[cur];

        // ---- phase 0: A-mh0 (8 reads) + B-n0,n1 (4 reads); MFMA mh0 x n0,n1 ----
#pragma unroll
        for (int ks = 0; ks < 2; ++ks) {
#pragma unroll
            for (int m = 0; m < 4; ++m)
                aF[ks][m] = *(const short8*)&Ab[(wr * 128 + m * 16 + fr) * 64 + (((ks * 4 + g4) ^ sw) * 8)];
#pragma unroll
            for (int n = 0; n < 2; ++n)
                bF[ks][n] = *(const short8*)&Bb[(wc * 64 + n * 16 + fr) * 64 + (((ks * 4 + g4) ^ sw) * 8)];
        }
        asm volatile("s_waitcnt lgkmcnt(0)" ::: "memory");
        __builtin_amdgcn_sched_barrier(0);
        __builtin_amdgcn_s_setprio(1);
#pragma unroll
        for (int ks = 0; ks < 2; ++ks)
#pragma unroll
            for (int m = 0; m < 4; ++m)
#pragma unroll
                for (int n = 0; n < 2; ++n)
                    acc[m][n] = MFMA_BF16(aF[ks][m], bF[ks][n], acc[m][n], 0, 0, 0);
        __builtin_amdgcn_s_setprio(0);
        __builtin_amdgcn_s_barrier();
        __builtin_amdgcn_sched_barrier(0);

        // ---- phase 1: B-n2,n3 (4 reads); MFMA mh0 x n2,n3 ----
#pragma unroll
        for (int ks = 0; ks < 2; ++ks)
#pragma unroll
            for (int n = 2; n < 4; ++n)
                bF[ks][n] = *(const short8*)&Bb[(wc * 64 + n * 16 + fr) * 64 + (((ks * 4 + g4) ^ sw) * 8)];
        asm volatile("s_waitcnt lgkmcnt(0)" ::: "memory");
        __builtin_amdgcn_sched_barrier(0);
        __builtin_amdgcn_s_setprio(1);
#pragma unroll
        for (int ks = 0; ks < 2; ++ks)
#pragma unroll
            for (int m = 0; m < 4; ++m)
#pragma unroll
                for (int n = 2; n < 4; ++n)
                    acc[m][n] = MFMA_BF16(aF[ks][m], bF[ks][n], acc[m][n], 0, 0, 0);
        __builtin_amdgcn_s_setprio(0);
        __builtin_amdgcn_s_barrier();
        __builtin_amdgcn_sched_barrier(0);

        // ---- phase 2: A-mh1 (8 reads); MFMA mh1 x n0,n1 ----
#pragma unroll
        for (int ks = 0; ks < 2; ++ks)
#pragma unroll
            for (int m = 0; m < 4; ++m)
                aF[ks][m] = *(const short8*)&Ab[(wr * 128 + 64 + m * 16 + fr) * 64 + (((ks * 4 + g4) ^ sw) * 8)];
        asm volatile("s_waitcnt lgkmcnt(0)" ::: "memory");
        __builtin_amdgcn_sched_barrier(0);
        __builtin_amdgcn_s_setprio(1);
#pragma unroll
        for (int ks = 0; ks < 2; ++ks)
#pragma unroll
            for (int m = 0; m < 4; ++m)
#pragma unroll
                for (int n = 0; n < 2; ++n)
                    acc[4 + m][n] = MFMA_BF16(aF[ks][m], bF[ks][n], acc[4 + m][n], 0, 0, 0);
        __builtin_amdgcn_s_setprio(0);
        __builtin_amdgcn_s_barrier();
        __builtin_amdgcn_sched_barrier(0);

        // ---- phase 3: no reads; MFMA mh1 x n2,n3 ----
        __builtin_amdgcn_s_setprio(1);
#pragma unroll
        for (int ks = 0; ks < 2; ++ks)
#pragma unroll
            for (int m = 0; m < 4; ++m)
#pragma unroll
                for (int n = 2; n < 4; ++n)
                    acc[4 + m][n] = MFMA_BF16(aF[ks][m], bF[ks][n], acc[4 + m][n], 0, 0, 0);
        __builtin_amdgcn_s_setprio(0);
        // next iteration's p0 provides the closing vmcnt+barrier
    }
}

// ---------------- GEMM1: H = gelu(Xg @ W1[e]^T + b1[e]) ----------------
#define G1_NX (FF / 256)                 // 16
#define G1_NWG (G1_NX * MB_MAX * NE)     // 4096
__global__ __launch_bounds__(512, 2) void gemm1_k(const short* __restrict__ xb,
                                                  const short* __restrict__ W1b,
                                                  const float* __restrict__ b1,
                                                  const int* __restrict__ cnt,
                                                  const int* __restrict__ offs,
                                                  const int* __restrict__ ptok,
                                                  short* __restrict__ H) {
    __shared__ __align__(16) short As[2][16384];
    __shared__ __align__(16) short Bs[2][16384];
    int wg = (blockIdx.x % 8) * (G1_NWG / 8) + blockIdx.x / 8;   // XCD swizzle (bijective)
    const int n0 = (wg % G1_NX) * 256;  wg /= G1_NX;
    const int m0 = (wg % MB_MAX) * 256; wg /= MB_MAX;
    const int e = wg;
    const int cnt_e = cnt[e], offs_e = offs[e];
    if (m0 >= cnt_e) return;

    f32x4 acc[8][4];
    gemm_core256<DIM, true>(xb, ptok, W1b + (size_t)e * FF * DIM, offs_e, cnt_e, m0, n0, acc, As, Bs);

    const int lane = threadIdx.x & 63, wave = threadIdx.x >> 6;
    const int wr = wave >> 2, wc = wave & 3;
    const int colb = lane & 15, rowb = (lane >> 4) * 4;
    float b1v[4];
#pragma unroll
    for (int n = 0; n < 4; ++n) b1v[n] = b1[e * FF + n0 + wc * 64 + n * 16 + colb];
#pragma unroll
    for (int m = 0; m < 8; ++m) {
#pragma unroll
        for (int r = 0; r < 4; ++r) {
            const int gm = m0 + wr * 128 + m * 16 + rowb + r;
            if (gm >= cnt_e) continue;
#pragma unroll
            for (int n = 0; n < 4; ++n) {
                const int col = n0 + wc * 64 + n * 16 + colb;
                float v = acc[m][n][r] + b1v[n];
                v = 0.5f * v * (1.f + erff(v * 0.70710678118f));
                H[(size_t)(offs_e + gm) * FF + col] = bf16_of(v);
            }
        }
    }
}

// ---------------- GEMM2: y[slot] = H @ W2[e]^T + b2[e] ----------------
#define G2_NX (DIM / 256)                // 4
#define G2_NWG (G2_NX * MB_MAX * NE)     // 1024
__global__ __launch_bounds__(512, 2) void gemm2_k(const short* __restrict__ H,
                                                  const short* __restrict__ W2b,
                                                  const float* __restrict__ b2,
                                                  const int* __restrict__ cnt,
                                                  const int* __restrict__ offs,
                                                  float* __restrict__ y) {
    __shared__ __align__(16) short As[2][16384];
    __shared__ __align__(16) short Bs[2][16384];
    int wg = (blockIdx.x % 8) * (G2_NWG / 8) + blockIdx.x / 8;
    const int n0 = (wg % G2_NX) * 256;  wg /= G2_NX;
    const int m0 = (wg % MB_MAX) * 256; wg /= MB_MAX;
    const int e = wg;
    const int cnt_e = cnt[e], offs_e = offs[e];
    if (m0 >= cnt_e) return;

    f32x4 acc[8][4];
    gemm_core256<FF, false>(H, nullptr, W2b + (size_t)e * DIM * FF, offs_e, cnt_e, m0, n0, acc, As, Bs);

    const int lane = threadIdx.x & 63, wave = threadIdx.x >> 6;
    const int wr = wave >> 2, wc = wave & 3;
    const int colb = lane & 15, rowb = (lane >> 4) * 4;
    float b2v[4];
#pragma unroll
    for (int n = 0; n < 4; ++n) b2v[n] = b2[e * DIM + n0 + wc * 64 + n * 16 + colb];
#pragma unroll
    for (int m = 0; m < 8; ++m) {
#pragma unroll
        for (int r = 0; r < 4; ++r) {
            const int gm = m0 + wr * 128 + m * 16 + rowb + r;
            if (gm >= cnt_e) continue;
#pragma unroll
            for (int n = 0; n < 4; ++n) {
                const int col = n0 + wc * 64 + n * 16 + colb;
                y[(size_t)(offs_e + gm) * DIM + col] = acc[m][n][r] + b2v[n];
            }
        }
    }
}

// ---------------- combine: out[t] = w1*y[s1] + w2*y[s2] ----------------
__global__ __launch_bounds__(256) void combine_k(const float* __restrict__ y,
                                                 const int* __restrict__ slot_of,
                                                 const float* __restrict__ a_w,
                                                 float* __restrict__ out) {
    const int t = blockIdx.x;
    const int c = threadIdx.x;
    const int s1 = slot_of[2 * t], s2 = slot_of[2 * t + 1];
    const float w1 = a_w[2 * t], w2 = a_w[2 * t + 1];
    float4 v1 = ((const float4*)(y + (size_t)s1 * DIM))[c];
    float4 v2 = ((const float4*)(y + (size_t)s2 * DIM))[c];
    float4 o;
    o.x = w1 * v1.x + w2 * v2.x;
    o.y = w1 * v1.y + w2 * v2.y;
    o.z = w1 * v1.z + w2 * v2.z;
    o.w = w1 * v1.w + w2 * v2.w;
    ((float4*)(out + (size_t)t * DIM))[c] = o;
}

// ---------------- launch ----------------
extern "C" void kernel_launch(void* const* d_in, const int* in_sizes, int n_in,
                              void* d_out, int out_size, void* d_ws, size_t ws_size,
                              hipStream_t stream) {
    const float* x  = (const float*)d_in[0];
    const float* Wr = (const float*)d_in[1];
    const float* W1 = (const float*)d_in[2];
    const float* b1 = (const float*)d_in[3];
    const float* W2 = (const float*)d_in[4];
    const float* b2 = (const float*)d_in[5];
    float* out = (float*)d_out;

    char* w = (char*)d_ws;
    int*   cnt     = (int*)w;
    int*   offs    = (int*)(w + 64);
    int*   a_exp   = (int*)(w + 128);
    int*   a_pos   = a_exp + NASSIGN;
    int*   ptok    = a_pos + NASSIGN;
    int*   slot_of = ptok + NASSIGN;
    float* a_w     = (float*)(slot_of + NASSIGN);
    float* pw      = a_w + NASSIGN;
    char*  p       = (char*)(pw + NASSIGN);
    p = (char*)(((uintptr_t)p + 255) & ~(uintptr_t)255);
    short* xb  = (short*)p;                p += (size_t)NTOK * DIM * 2;
    short* W1b = (short*)p;                p += (size_t)NE * FF * DIM * 2;
    short* W2b = (short*)p;                p += (size_t)NE * DIM * FF * 2;
    short* H   = (short*)p;                // NASSIGN * FF * 2 = 134 MB
    // y aliases W1b (dead after gemm1); NASSIGN*DIM*4 == NE*FF*DIM*2
    float* y   = (float*)W1b;

    hipMemsetAsync(cnt, 0, 32, stream);

    cvt_k<<<(NTOK * DIM / 8 + 255) / 256, 256, 0, stream>>>(x, xb, NTOK * DIM / 8);
    cvt_k<<<(NE * FF * DIM / 8 + 255) / 256, 256, 0, stream>>>(W1, W1b, NE * FF * DIM / 8);
    cvt_k<<<(NE * DIM * FF / 8 + 255) / 256, 256, 0, stream>>>(W2, W2b, NE * DIM * FF / 8);

    router_k<<<NTOK, 64, 0, stream>>>(x, Wr, cnt, a_exp, a_pos, a_w);
    offsets_k<<<1, 64, 0, stream>>>(cnt, offs);
    scatter_k<<<NASSIGN / 256, 256, 0, stream>>>(a_exp, a_pos, a_w, offs, ptok, pw, slot_of);

    gemm1_k<<<G1_NWG, 512, 0, stream>>>(xb, W1b, b1, cnt, offs, ptok, H);
    gemm2_k<<<G2_NWG, 512, 0, stream>>>(H, W2b, b2, cnt, offs, y);
    combine_k<<<NTOK, 256, 0, stream>>>(y, slot_of, a_w, out);
}

// Round 7
// 752.610 us; speedup vs baseline: 1.1994x; 1.1572x over previous
//
#include <hip/hip_runtime.h>
#include <hip/hip_bf16.h>
#include <math.h>
#include <stdint.h>

#define DIM 1024
#define FF 4096
#define NE 8
#define NTOK 8192
#define NASSIGN (NTOK * 2)
#define MB_MAX (NTOK / 256)     // 32 max m-blocks per expert

typedef short short8 __attribute__((ext_vector_type(8)));
typedef float f32x4 __attribute__((ext_vector_type(4)));

static __device__ __forceinline__ short bf16_of(float f) {
    union { float f; unsigned u; } v; v.f = f;
    unsigned r = v.u + 0x7fffu + ((v.u >> 16) & 1u);   // RNE
    return (short)(r >> 16);
}

static __device__ __forceinline__ short8 cvt8(float4 a, float4 b) {
    short8 r;
    r[0] = bf16_of(a.x); r[1] = bf16_of(a.y); r[2] = bf16_of(a.z); r[3] = bf16_of(a.w);
    r[4] = bf16_of(b.x); r[5] = bf16_of(b.y); r[6] = bf16_of(b.z); r[7] = bf16_of(b.w);
    return r;
}

static __device__ __forceinline__ void gl_lds16(const short* g, short* lds) {
    __builtin_amdgcn_global_load_lds(
        (const __attribute__((address_space(1))) void*)g,
        (__attribute__((address_space(3))) void*)lds, 16, 0, 0);
}

// ---------------- f32 -> bf16 bulk convert ----------------
__global__ __launch_bounds__(256) void cvt_k(const float* __restrict__ in,
                                             short* __restrict__ out, int n8) {
    int i = blockIdx.x * blockDim.x + threadIdx.x;
    if (i >= n8) return;
    float4 a = ((const float4*)in)[2 * i];
    float4 b = ((const float4*)in)[2 * i + 1];
    ((short8*)out)[i] = cvt8(a, b);
}

// ---------------- router ----------------
__global__ void router_k(const float* __restrict__ x, const float* __restrict__ Wr,
                         int* __restrict__ cnt, int* __restrict__ a_exp,
                         int* __restrict__ a_pos, float* __restrict__ a_w) {
    int t = blockIdx.x;
    int lane = threadIdx.x;
    const float* xr = x + (size_t)t * DIM;
    float p[NE];
#pragma unroll
    for (int e = 0; e < NE; ++e) p[e] = 0.f;
    for (int i = 0; i < DIM / 64; ++i) {
        float xv = xr[lane + i * 64];
#pragma unroll
        for (int e = 0; e < NE; ++e) p[e] += xv * Wr[e * DIM + lane + i * 64];
    }
#pragma unroll
    for (int off = 32; off >= 1; off >>= 1)
#pragma unroll
        for (int e = 0; e < NE; ++e) p[e] += __shfl_xor(p[e], off);
    if (lane == 0) {
        float mx = p[0];
#pragma unroll
        for (int e = 1; e < NE; ++e) mx = fmaxf(mx, p[e]);
        float pr[NE]; float s = 0.f;
#pragma unroll
        for (int e = 0; e < NE; ++e) { pr[e] = expf(p[e] - mx); s += pr[e]; }
#pragma unroll
        for (int e = 0; e < NE; ++e) pr[e] /= s;
        int i1 = 0;
#pragma unroll
        for (int e = 1; e < NE; ++e) if (pr[e] > pr[i1]) i1 = e;
        int i2 = (i1 == 0) ? 1 : 0;
#pragma unroll
        for (int e = 0; e < NE; ++e) if (e != i1 && pr[e] > pr[i2]) i2 = e;
        float w1 = pr[i1], w2 = pr[i2], nrm = w1 + w2;
        w1 /= nrm; w2 /= nrm;
        int p1 = atomicAdd(&cnt[i1], 1);
        int p2 = atomicAdd(&cnt[i2], 1);
        a_exp[2 * t] = i1;     a_pos[2 * t] = p1;     a_w[2 * t] = w1;
        a_exp[2 * t + 1] = i2; a_pos[2 * t + 1] = p2; a_w[2 * t + 1] = w2;
    }
}

__global__ void offsets_k(const int* __restrict__ cnt, int* __restrict__ offs) {
    if (threadIdx.x == 0) {
        int s = 0;
        for (int e = 0; e < NE; ++e) { offs[e] = s; s += cnt[e]; }
        offs[NE] = s;
    }
}

__global__ void scatter_k(const int* __restrict__ a_exp, const int* __restrict__ a_pos,
                          const float* __restrict__ a_w, const int* __restrict__ offs,
                          int* __restrict__ ptok, float* __restrict__ pw,
                          int* __restrict__ slot_of) {
    int a = blockIdx.x * blockDim.x + threadIdx.x;
    if (a >= NASSIGN) return;
    int e = a_exp[a];
    int r = offs[e] + a_pos[a];
    ptok[r] = a >> 1;
    pw[r] = a_w[a];
    slot_of[a] = r;
}

// ======== 256x256 grouped GEMM core, BK=64, 4 phases/K-tile, counted vmcnt ========
// LDS: 2 K-tile buffers (A 256x64 + B 256x64 bf16) = 128 KB. 8 waves (2M x 4N).
// Swizzle: LDS[row][slot] = global[row][slot ^ (row&7)] (16B slots, 8/row) -> 0 conflicts.
// Half-tiles (aligned to phase needs):
//   Ah0 = A rows {0-63,128-191}   (mh0 frags)   staged @ p1
//   Ba  = B rows {(row&63)<32}    (n0,n1 frags) staged @ p2
//   Bb  = B rows {(row&63)>=32}   (n2,n3 frags) staged @ p3
//   Ah1 = A rows {64-127,192-255} (mh1 frags)   staged @ p4
// Steady-state waits (2 loads per half; issue order ...Bb_t Ah1_t | Ah0_t+1 Ba_t+1 Bb_t+1 Ah1_t+1):
//   p1: need Bb_t   -> allow {Ah1_t, Ah0_t+1}  = vmcnt(4)
//   p2: need Ah1_t  -> allow {Ah0_t+1, Ba_t+1} = vmcnt(4)
//   p3: none
//   p4: need Ah0_t+1,Ba_t+1 -> allow {Bb_t+1, Ah1_t+1} = vmcnt(4)
// TAIL (t == NK-1, no staging): vmcnt(4) would be satisfied with Bb_t/Ah1_t still in
// flight (round-6 bug). Fix: p1 drains vmcnt(0); p2/p4 skip waits.
#define MFMA_BF16 __builtin_amdgcn_mfma_f32_16x16x32_bf16
#define SBAR0 __builtin_amdgcn_sched_barrier(0)

template <int KROW, int KCH, bool GATHER>
__device__ __forceinline__ void gemm8p(const short* __restrict__ A,
                                       const int* __restrict__ ptok,
                                       const short* __restrict__ B,
                                       int offs_e, int cnt_e, int m0, int n0, int k0,
                                       f32x4 acc[8][4],
                                       short (*As)[16384], short (*Bs)[16384]) {
    const int tid = threadIdx.x;
    const int lane = tid & 63, wave = tid >> 6;
    const int wr = wave >> 2, wc = wave & 3;

#pragma unroll
    for (int m = 0; m < 8; ++m)
#pragma unroll
        for (int n = 0; n < 4; ++n) acc[m][n] = (f32x4){0.f, 0.f, 0.f, 0.f};

    const int srow = tid >> 3, sslot = tid & 7;
    const int gsl8 = (sslot ^ (srow & 7)) * 8;      // inverse-swizzled global 16B slot

    int ra0 = m0 + srow;       if (ra0 >= cnt_e) ra0 = cnt_e - 1;   // Ah0
    int ra2 = m0 + srow + 128; if (ra2 >= cnt_e) ra2 = cnt_e - 1;   // Ah0
    int ra1 = m0 + srow + 64;  if (ra1 >= cnt_e) ra1 = cnt_e - 1;   // Ah1
    int ra3 = m0 + srow + 192; if (ra3 >= cnt_e) ra3 = cnt_e - 1;   // Ah1
    const short* aR0 = A + (GATHER ? (size_t)ptok[offs_e + ra0] : (size_t)(offs_e + ra0)) * KROW + k0 + gsl8;
    const short* aR2 = A + (GATHER ? (size_t)ptok[offs_e + ra2] : (size_t)(offs_e + ra2)) * KROW + k0 + gsl8;
    const short* aR1 = A + (GATHER ? (size_t)ptok[offs_e + ra1] : (size_t)(offs_e + ra1)) * KROW + k0 + gsl8;
    const short* aR3 = A + (GATHER ? (size_t)ptok[offs_e + ra3] : (size_t)(offs_e + ra3)) * KROW + k0 + gsl8;
    const int br = (srow & 31) + (srow >> 5) * 64;
    const short* bRa0 = B + (size_t)(n0 + br) * KROW + k0 + gsl8;
    const short* bRa1 = B + (size_t)(n0 + br + 128) * KROW + k0 + gsl8;
    const short* bRb0 = B + (size_t)(n0 + br + 32) * KROW + k0 + gsl8;
    const short* bRb1 = B + (size_t)(n0 + br + 160) * KROW + k0 + gsl8;
    const int lA0a = tid * 8,                 lA0b = (tid + 1024) * 8;
    const int lA1a = (tid + 512) * 8,         lA1b = (tid + 1536) * 8;
    const int lBaa = (br * 8 + sslot) * 8,    lBab = ((br + 128) * 8 + sslot) * 8;
    const int lBba = ((br + 32) * 8 + sslot) * 8, lBbb = ((br + 160) * 8 + sslot) * 8;

    const int fr = lane & 15, g4 = lane >> 4, swz = fr & 7;
    const int NK = KCH / 64;
    short8 aF[2][4], bF[2][4];

    // prologue: full tile 0 (Ah0, Ba, Bb, Ah1); ensure Ah0_0, Ba_0 resident
    gl_lds16(aR0, &As[0][lA0a]); gl_lds16(aR2, &As[0][lA0b]);
    gl_lds16(bRa0, &Bs[0][lBaa]); gl_lds16(bRa1, &Bs[0][lBab]);
    gl_lds16(bRb0, &Bs[0][lBba]); gl_lds16(bRb1, &Bs[0][lBbb]);
    gl_lds16(aR1, &As[0][lA1a]); gl_lds16(aR3, &As[0][lA1b]);
    asm volatile("s_waitcnt vmcnt(4)" ::: "memory");
    SBAR0;
    __builtin_amdgcn_s_barrier();

    for (int t = 0; t < NK; ++t) {
        const int cur = t & 1, nxt = cur ^ 1;
        const short* Ab = As[cur];
        const short* Bb2 = Bs[cur];
        const int co = (t + 1) * 64;
        const bool pf = (t + 1 < NK);

        // ---------- phase 1: read Ah0 + B n0,n1; stage Ah0_{t+1} ----------
#pragma unroll
        for (int ks = 0; ks < 2; ++ks) {
#pragma unroll
            for (int m = 0; m < 4; ++m)
                aF[ks][m] = *(const short8*)&Ab[((wr * 128 + m * 16 + fr) * 8 + ((ks * 4 + g4) ^ swz)) * 8];
#pragma unroll
            for (int n = 0; n < 2; ++n)
                bF[ks][n] = *(const short8*)&Bb2[((wc * 64 + n * 16 + fr) * 8 + ((ks * 4 + g4) ^ swz)) * 8];
        }
        if (pf) {
            gl_lds16(aR0 + co, &As[nxt][lA0a]); gl_lds16(aR2 + co, &As[nxt][lA0b]);
            asm volatile("s_waitcnt vmcnt(4)" ::: "memory");   // Bb_t landed
        } else {
            asm volatile("s_waitcnt vmcnt(0)" ::: "memory");   // TAIL: drain Bb_t, Ah1_t
        }
        SBAR0;
        __builtin_amdgcn_s_barrier();
        asm volatile("s_waitcnt lgkmcnt(0)" ::: "memory");
        SBAR0;
        __builtin_amdgcn_s_setprio(1);
#pragma unroll
        for (int ks = 0; ks < 2; ++ks)
#pragma unroll
            for (int m = 0; m < 4; ++m)
#pragma unroll
                for (int n = 0; n < 2; ++n)
                    acc[m][n] = MFMA_BF16(aF[ks][m], bF[ks][n], acc[m][n], 0, 0, 0);
        __builtin_amdgcn_s_setprio(0);

        // ---------- phase 2: read B n2,n3; stage Ba_{t+1} ----------
#pragma unroll
        for (int ks = 0; ks < 2; ++ks)
#pragma unroll
            for (int n = 2; n < 4; ++n)
                bF[ks][n] = *(const short8*)&Bb2[((wc * 64 + n * 16 + fr) * 8 + ((ks * 4 + g4) ^ swz)) * 8];
        if (pf) {
            gl_lds16(bRa0 + co, &Bs[nxt][lBaa]); gl_lds16(bRa1 + co, &Bs[nxt][lBab]);
            asm volatile("s_waitcnt vmcnt(4)" ::: "memory");   // Ah1_t landed
        }
        SBAR0;
        __builtin_amdgcn_s_barrier();
        asm volatile("s_waitcnt lgkmcnt(0)" ::: "memory");
        SBAR0;
        __builtin_amdgcn_s_setprio(1);
#pragma unroll
        for (int ks = 0; ks < 2; ++ks)
#pragma unroll
            for (int m = 0; m < 4; ++m)
#pragma unroll
                for (int n = 2; n < 4; ++n)
                    acc[m][n] = MFMA_BF16(aF[ks][m], bF[ks][n], acc[m][n], 0, 0, 0);
        __builtin_amdgcn_s_setprio(0);

        // ---------- phase 3: read Ah1; stage Bb_{t+1}; no wait ----------
#pragma unroll
        for (int ks = 0; ks < 2; ++ks)
#pragma unroll
            for (int m = 0; m < 4; ++m)
                aF[ks][m] = *(const short8*)&Ab[((wr * 128 + 64 + m * 16 + fr) * 8 + ((ks * 4 + g4) ^ swz)) * 8];
        if (pf) { gl_lds16(bRb0 + co, &Bs[nxt][lBba]); gl_lds16(bRb1 + co, &Bs[nxt][lBbb]); }
        __builtin_amdgcn_s_barrier();
        asm volatile("s_waitcnt lgkmcnt(0)" ::: "memory");
        SBAR0;
        __builtin_amdgcn_s_setprio(1);
#pragma unroll
        for (int ks = 0; ks < 2; ++ks)
#pragma unroll
            for (int m = 0; m < 4; ++m)
#pragma unroll
                for (int n = 0; n < 2; ++n)
                    acc[4 + m][n] = MFMA_BF16(aF[ks][m], bF[ks][n], acc[4 + m][n], 0, 0, 0);
        __builtin_amdgcn_s_setprio(0);

        // ---------- phase 4: no reads; stage Ah1_{t+1} ----------
        if (pf) {
            gl_lds16(aR1 + co, &As[nxt][lA1a]); gl_lds16(aR3 + co, &As[nxt][lA1b]);
            asm volatile("s_waitcnt vmcnt(4)" ::: "memory");   // Ah0_{t+1}, Ba_{t+1} landed
        }
        SBAR0;
        __builtin_amdgcn_s_barrier();
        __builtin_amdgcn_s_setprio(1);
#pragma unroll
        for (int ks = 0; ks < 2; ++ks)
#pragma unroll
            for (int m = 0; m < 4; ++m)
#pragma unroll
                for (int n = 2; n < 4; ++n)
                    acc[4 + m][n] = MFMA_BF16(aF[ks][m], bF[ks][n], acc[4 + m][n], 0, 0, 0);
        __builtin_amdgcn_s_setprio(0);
    }
}

// ---------------- GEMM1: H = gelu(Xg @ W1[e]^T + b1[e]) ----------------
#define G1_NX (FF / 256)                 // 16
#define G1_NWG (G1_NX * MB_MAX * NE)     // 4096
__global__ __launch_bounds__(512, 2) void gemm1_k(const short* __restrict__ xb,
                                                  const short* __restrict__ W1b,
                                                  const float* __restrict__ b1,
                                                  const int* __restrict__ cnt,
                                                  const int* __restrict__ offs,
                                                  const int* __restrict__ ptok,
                                                  short* __restrict__ H) {
    __shared__ __align__(16) short As[2][16384];
    __shared__ __align__(16) short Bs[2][16384];
    int wg = (blockIdx.x % 8) * (G1_NWG / 8) + blockIdx.x / 8;   // bijective XCD swizzle
    const int n0 = (wg % G1_NX) * 256;  wg /= G1_NX;
    const int m0 = (wg % MB_MAX) * 256; wg /= MB_MAX;
    const int e = wg;
    const int cnt_e = cnt[e], offs_e = offs[e];
    if (m0 >= cnt_e) return;

    f32x4 acc[8][4];
    gemm8p<DIM, DIM, true>(xb, ptok, W1b + (size_t)e * FF * DIM, offs_e, cnt_e, m0, n0, 0, acc, As, Bs);

    const int lane = threadIdx.x & 63, wave = threadIdx.x >> 6;
    const int wr = wave >> 2, wc = wave & 3;
    const int colb = lane & 15, rowb = (lane >> 4) * 4;
    float b1v[4];
#pragma unroll
    for (int n = 0; n < 4; ++n) b1v[n] = b1[e * FF + n0 + wc * 64 + n * 16 + colb];
#pragma unroll
    for (int m = 0; m < 8; ++m) {
#pragma unroll
        for (int r = 0; r < 4; ++r) {
            const int gm = m0 + wr * 128 + m * 16 + rowb + r;
            if (gm >= cnt_e) continue;
#pragma unroll
            for (int n = 0; n < 4; ++n) {
                const int col = n0 + wc * 64 + n * 16 + colb;
                float v = acc[m][n][r] + b1v[n];
                v = 0.5f * v * (1.f + erff(v * 0.70710678118f));
                H[(size_t)(offs_e + gm) * FF + col] = bf16_of(v);
            }
        }
    }
}

// ------------- GEMM2: ypart = H[:, kslice] @ W2[e][:, kslice]^T  (b2 in combine) -------------
#define G2_NX (DIM / 256)                // 4
template <int KCH>
__global__ __launch_bounds__(512, 2) void gemm2_k(const short* __restrict__ H,
                                                  const short* __restrict__ W2b,
                                                  const int* __restrict__ cnt,
                                                  const int* __restrict__ offs,
                                                  float* __restrict__ y0,
                                                  float* __restrict__ y1,
                                                  int nwg) {
    __shared__ __align__(16) short As[2][16384];
    __shared__ __align__(16) short Bs[2][16384];
    const int KS = FF / KCH;
    int wg = (blockIdx.x % 8) * (nwg / 8) + blockIdx.x / 8;
    int nk = wg % (G2_NX * KS); wg /= (G2_NX * KS);
    const int n0 = (nk % G2_NX) * 256;
    const int kslice = nk / G2_NX;
    const int m0 = (wg % MB_MAX) * 256; wg /= MB_MAX;
    const int e = wg;
    const int cnt_e = cnt[e], offs_e = offs[e];
    if (m0 >= cnt_e) return;

    f32x4 acc[8][4];
    gemm8p<FF, KCH, false>(H, nullptr, W2b + (size_t)e * DIM * FF, offs_e, cnt_e, m0, n0,
                           kslice * KCH, acc, As, Bs);

    float* y = kslice ? y1 : y0;
    const int lane = threadIdx.x & 63, wave = threadIdx.x >> 6;
    const int wr = wave >> 2, wc = wave & 3;
    const int colb = lane & 15, rowb = (lane >> 4) * 4;
#pragma unroll
    for (int m = 0; m < 8; ++m) {
#pragma unroll
        for (int r = 0; r < 4; ++r) {
            const int gm = m0 + wr * 128 + m * 16 + rowb + r;
            if (gm >= cnt_e) continue;
#pragma unroll
            for (int n = 0; n < 4; ++n) {
                const int col = n0 + wc * 64 + n * 16 + colb;
                y[(size_t)(offs_e + gm) * DIM + col] = acc[m][n][r];
            }
        }
    }
}

// -------- combine: out[t] = w1*(ysum(s1)+b2[e1]) + w2*(ysum(s2)+b2[e2]) --------
__global__ __launch_bounds__(256) void combine_k(const float* __restrict__ y0,
                                                 const float* __restrict__ y1,
                                                 int ks,
                                                 const int* __restrict__ slot_of,
                                                 const int* __restrict__ a_exp,
                                                 const float* __restrict__ a_w,
                                                 const float* __restrict__ b2,
                                                 float* __restrict__ out) {
    const int t = blockIdx.x;
    const int c = threadIdx.x;
    const int s1 = slot_of[2 * t], s2 = slot_of[2 * t + 1];
    const int e1 = a_exp[2 * t], e2 = a_exp[2 * t + 1];
    const float w1 = a_w[2 * t], w2 = a_w[2 * t + 1];
    float4 v1 = ((const float4*)(y0 + (size_t)s1 * DIM))[c];
    float4 v2 = ((const float4*)(y0 + (size_t)s2 * DIM))[c];
    if (ks == 2) {
        float4 u1 = ((const float4*)(y1 + (size_t)s1 * DIM))[c];
        float4 u2 = ((const float4*)(y1 + (size_t)s2 * DIM))[c];
        v1.x += u1.x; v1.y += u1.y; v1.z += u1.z; v1.w += u1.w;
        v2.x += u2.x; v2.y += u2.y; v2.z += u2.z; v2.w += u2.w;
    }
    float4 g1 = ((const float4*)(b2 + (size_t)e1 * DIM))[c];
    float4 g2 = ((const float4*)(b2 + (size_t)e2 * DIM))[c];
    float4 o;
    o.x = w1 * (v1.x + g1.x) + w2 * (v2.x + g2.x);
    o.y = w1 * (v1.y + g1.y) + w2 * (v2.y + g2.y);
    o.z = w1 * (v1.z + g1.z) + w2 * (v2.z + g2.z);
    o.w = w1 * (v1.w + g1.w) + w2 * (v2.w + g2.w);
    ((float4*)(out + (size_t)t * DIM))[c] = o;
}

// ---------------- launch ----------------
extern "C" void kernel_launch(void* const* d_in, const int* in_sizes, int n_in,
                              void* d_out, int out_size, void* d_ws, size_t ws_size,
                              hipStream_t stream) {
    const float* x  = (const float*)d_in[0];
    const float* Wr = (const float*)d_in[1];
    const float* W1 = (const float*)d_in[2];
    const float* b1 = (const float*)d_in[3];
    const float* W2 = (const float*)d_in[4];
    const float* b2 = (const float*)d_in[5];
    float* out = (float*)d_out;

    char* w = (char*)d_ws;
    int*   cnt     = (int*)w;
    int*   offs    = (int*)(w + 64);
    int*   a_exp   = (int*)(w + 128);
    int*   a_pos   = a_exp + NASSIGN;
    int*   ptok    = a_pos + NASSIGN;
    int*   slot_of = ptok + NASSIGN;
    float* a_w     = (float*)(slot_of + NASSIGN);
    float* pw      = a_w + NASSIGN;
    char*  p       = (char*)(pw + NASSIGN);
    p = (char*)(((uintptr_t)p + 255) & ~(uintptr_t)255);
    short* xb  = (short*)p;                p += (size_t)NTOK * DIM * 2;
    short* W1b = (short*)p;                p += (size_t)NE * FF * DIM * 2;
    short* W2b = (short*)p;                p += (size_t)NE * DIM * FF * 2;
    short* H   = (short*)p;                p += (size_t)NASSIGN * FF * 2;   // 134 MB
    // y0 aliases W1b (dead after gemm1); NASSIGN*DIM*4 == NE*FF*DIM*2
    float* y0  = (float*)W1b;
    float* y1  = (float*)p;                p += (size_t)NASSIGN * DIM * 4;  // 67 MB (split-K partial)
    const int ks = ((size_t)(p - w) <= ws_size) ? 2 : 1;

    hipMemsetAsync(cnt, 0, 32, stream);

    cvt_k<<<(NTOK * DIM / 8 + 255) / 256, 256, 0, stream>>>(x, xb, NTOK * DIM / 8);
    cvt_k<<<(NE * FF * DIM / 8 + 255) / 256, 256, 0, stream>>>(W1, W1b, NE * FF * DIM / 8);
    cvt_k<<<(NE * DIM * FF / 8 + 255) / 256, 256, 0, stream>>>(W2, W2b, NE * DIM * FF / 8);

    router_k<<<NTOK, 64, 0, stream>>>(x, Wr, cnt, a_exp, a_pos, a_w);
    offsets_k<<<1, 64, 0, stream>>>(cnt, offs);
    scatter_k<<<NASSIGN / 256, 256, 0, stream>>>(a_exp, a_pos, a_w, offs, ptok, pw, slot_of);

    gemm1_k<<<G1_NWG, 512, 0, stream>>>(xb, W1b, b1, cnt, offs, ptok, H);

    if (ks == 2) {
        const int nwg2 = G2_NX * 2 * MB_MAX * NE;   // 2048
        gemm2_k<FF / 2><<<nwg2, 512, 0, stream>>>(H, W2b, cnt, offs, y0, y1, nwg2);
    } else {
        const int nwg2 = G2_NX * MB_MAX * NE;       // 1024
        gemm2_k<FF><<<nwg2, 512, 0, stream>>>(H, W2b, cnt, offs, y0, y1, nwg2);
    }
    combine_k<<<NTOK, 256, 0, stream>>>(y0, y1, ks, slot_of, a_exp, a_w, b2, out);
}

// Round 8
// 695.170 us; speedup vs baseline: 1.2985x; 1.0826x over previous
//
#include <hip/hip_runtime.h>
#include <hip/hip_bf16.h>
#include <math.h>
#include <stdint.h>

#define DIM 1024
#define FF 4096
#define NE 8
#define NTOK 8192
#define NASSIGN (NTOK * 2)
#define MB_MAX (NTOK / 256)     // 32 max m-blocks per expert

typedef short short8 __attribute__((ext_vector_type(8)));
typedef float f32x4 __attribute__((ext_vector_type(4)));

static __device__ __forceinline__ short bf16_of(float f) {
    union { float f; unsigned u; } v; v.f = f;
    unsigned r = v.u + 0x7fffu + ((v.u >> 16) & 1u);   // RNE
    return (short)(r >> 16);
}

static __device__ __forceinline__ short8 cvt8(float4 a, float4 b) {
    short8 r;
    r[0] = bf16_of(a.x); r[1] = bf16_of(a.y); r[2] = bf16_of(a.z); r[3] = bf16_of(a.w);
    r[4] = bf16_of(b.x); r[5] = bf16_of(b.y); r[6] = bf16_of(b.z); r[7] = bf16_of(b.w);
    return r;
}

static __device__ __forceinline__ void gl_lds16(const short* g, short* lds) {
    __builtin_amdgcn_global_load_lds(
        (const __attribute__((address_space(1))) void*)g,
        (__attribute__((address_space(3))) void*)lds, 16, 0, 0);
}

// ---------------- f32 -> bf16 bulk convert ----------------
__global__ __launch_bounds__(256) void cvt_k(const float* __restrict__ in,
                                             short* __restrict__ out, int n8) {
    int i = blockIdx.x * blockDim.x + threadIdx.x;
    if (i >= n8) return;
    float4 a = ((const float4*)in)[2 * i];
    float4 b = ((const float4*)in)[2 * i + 1];
    ((short8*)out)[i] = cvt8(a, b);
}

// ---------------- router (fused: also emits xb = bf16(x)) ----------------
__global__ void router_k(const float* __restrict__ x, const float* __restrict__ Wr,
                         int* __restrict__ cnt, int* __restrict__ a_exp,
                         int* __restrict__ a_pos, float* __restrict__ a_w,
                         short* __restrict__ xb) {
    int t = blockIdx.x;
    int lane = threadIdx.x;
    const float* xr = x + (size_t)t * DIM;
    short* xbr = xb + (size_t)t * DIM;
    float p[NE];
#pragma unroll
    for (int e = 0; e < NE; ++e) p[e] = 0.f;
    for (int i = 0; i < DIM / 64; ++i) {
        float xv = xr[lane + i * 64];
        xbr[lane + i * 64] = bf16_of(xv);
#pragma unroll
        for (int e = 0; e < NE; ++e) p[e] += xv * Wr[e * DIM + lane + i * 64];
    }
#pragma unroll
    for (int off = 32; off >= 1; off >>= 1)
#pragma unroll
        for (int e = 0; e < NE; ++e) p[e] += __shfl_xor(p[e], off);
    if (lane == 0) {
        float mx = p[0];
#pragma unroll
        for (int e = 1; e < NE; ++e) mx = fmaxf(mx, p[e]);
        float pr[NE]; float s = 0.f;
#pragma unroll
        for (int e = 0; e < NE; ++e) { pr[e] = expf(p[e] - mx); s += pr[e]; }
#pragma unroll
        for (int e = 0; e < NE; ++e) pr[e] /= s;
        int i1 = 0;
#pragma unroll
        for (int e = 1; e < NE; ++e) if (pr[e] > pr[i1]) i1 = e;
        int i2 = (i1 == 0) ? 1 : 0;
#pragma unroll
        for (int e = 0; e < NE; ++e) if (e != i1 && pr[e] > pr[i2]) i2 = e;
        float w1 = pr[i1], w2 = pr[i2], nrm = w1 + w2;
        w1 /= nrm; w2 /= nrm;
        int p1 = atomicAdd(&cnt[i1], 1);
        int p2 = atomicAdd(&cnt[i2], 1);
        a_exp[2 * t] = i1;     a_pos[2 * t] = p1;     a_w[2 * t] = w1;
        a_exp[2 * t + 1] = i2; a_pos[2 * t + 1] = p2; a_w[2 * t + 1] = w2;
    }
}

__global__ void offsets_k(const int* __restrict__ cnt, int* __restrict__ offs) {
    if (threadIdx.x == 0) {
        int s = 0;
        for (int e = 0; e < NE; ++e) { offs[e] = s; s += cnt[e]; }
        offs[NE] = s;
    }
}

__global__ void scatter_k(const int* __restrict__ a_exp, const int* __restrict__ a_pos,
                          const float* __restrict__ a_w, const int* __restrict__ offs,
                          int* __restrict__ ptok, float* __restrict__ pw,
                          int* __restrict__ slot_of) {
    int a = blockIdx.x * blockDim.x + threadIdx.x;
    if (a >= NASSIGN) return;
    int e = a_exp[a];
    int r = offs[e] + a_pos[a];
    ptok[r] = a >> 1;
    pw[r] = a_w[a];
    slot_of[a] = r;
}

// ======== 256x256 grouped GEMM core, BK=64, 4 phases/K-tile, deep counted vmcnt ========
// LDS: 2 K-tile buffers (A 256x64 + B 256x64 bf16) = 128 KB. 8 waves (2M x 4N).
// Swizzle: LDS[row][slot] = global[row][slot ^ (row&7)] (16B slots, 8/row) -> 0 conflicts.
// Half-tiles: Ah0 = A rows {0-63,128-191}; Ah1 = {64-127,192-255};
//             Ba = B rows {(row&63)<32} (n01); Bb = {(row&63)>=32} (n23).
// ISSUE ORDER (steady): Ba_{t+1}@p1(t), Bb_{t+1}@p2(t), Ah1_{t+1}@p3(t), Ah0_{t+2}@p4(t).
// Each half gets 4-5 phases of flight time before its guaranteeing wait (m201 depth).
// WAITS (end of phase p guarantees phase p+1's LDS reads; FIFO vmcnt, 2 loads/half):
//  p1: need Bb_t (issued p2(t-1)); queue worst [Bb_t,Ah1_t,Ah0_{t+1},Ba_{t+1}] -> vmcnt(6)
//  p2: need Ah1_t (p3(t-1));  queue [Ah1_t,Ah0_{t+1},Ba_{t+1},Bb_{t+1}]        -> vmcnt(6)
//  p3: p4 reads nothing -> no wait
//  p4: need Ah0_{t+1}(p4(t-1)) & Ba_{t+1}(p1(t));
//      queue [Ah0_{t+1},Ba_{t+1},Bb_{t+1},Ah1_{t+1},Ah0_{t+2}]                 -> vmcnt(6)
// TAIL: t=NK-2: p4 stages nothing -> vmcnt(4). t=NK-1: p1 vmcnt(2), p2 vmcnt(0), p4 none.
// LDS WRITE HAZARDS: stages @p1-p3 target buf[nxt] (=tile t-1's buf) whose reads all
// drained before p4(t-1)'s barrier (each wave's p3 lgkmcnt(0) precedes it). Stage @p4
// targets As[cur] Ah0-region: Ah0/Ba/Bb reads of buf[cur] drained by p1/p2 lgkmcnt(0)
// which precede p3's barrier (< issue point); outstanding Ah1 reads touch a disjoint
// LDS region. All stage/stage pairs target disjoint regions.
#define MFMA_BF16 __builtin_amdgcn_mfma_f32_16x16x32_bf16
#define SBAR0 __builtin_amdgcn_sched_barrier(0)

template <int KROW, int KCH, bool GATHER>
__device__ __forceinline__ void gemm8p(const short* __restrict__ A,
                                       const int* __restrict__ ptok,
                                       const short* __restrict__ B,
                                       int offs_e, int cnt_e, int m0, int n0, int k0,
                                       f32x4 acc[8][4],
                                       short (*As)[16384], short (*Bs)[16384]) {
    const int tid = threadIdx.x;
    const int lane = tid & 63, wave = tid >> 6;
    const int wr = wave >> 2, wc = wave & 3;

#pragma unroll
    for (int m = 0; m < 8; ++m)
#pragma unroll
        for (int n = 0; n < 4; ++n) acc[m][n] = (f32x4){0.f, 0.f, 0.f, 0.f};

    const int srow = tid >> 3, sslot = tid & 7;
    const int gsl8 = (sslot ^ (srow & 7)) * 8;      // inverse-swizzled global 16B slot

    int ra0 = m0 + srow;       if (ra0 >= cnt_e) ra0 = cnt_e - 1;   // Ah0
    int ra2 = m0 + srow + 128; if (ra2 >= cnt_e) ra2 = cnt_e - 1;   // Ah0
    int ra1 = m0 + srow + 64;  if (ra1 >= cnt_e) ra1 = cnt_e - 1;   // Ah1
    int ra3 = m0 + srow + 192; if (ra3 >= cnt_e) ra3 = cnt_e - 1;   // Ah1
    const short* aR0 = A + (GATHER ? (size_t)ptok[offs_e + ra0] : (size_t)(offs_e + ra0)) * KROW + k0 + gsl8;
    const short* aR2 = A + (GATHER ? (size_t)ptok[offs_e + ra2] : (size_t)(offs_e + ra2)) * KROW + k0 + gsl8;
    const short* aR1 = A + (GATHER ? (size_t)ptok[offs_e + ra1] : (size_t)(offs_e + ra1)) * KROW + k0 + gsl8;
    const short* aR3 = A + (GATHER ? (size_t)ptok[offs_e + ra3] : (size_t)(offs_e + ra3)) * KROW + k0 + gsl8;
    const int br = (srow & 31) + (srow >> 5) * 64;
    const short* bRa0 = B + (size_t)(n0 + br) * KROW + k0 + gsl8;
    const short* bRa1 = B + (size_t)(n0 + br + 128) * KROW + k0 + gsl8;
    const short* bRb0 = B + (size_t)(n0 + br + 32) * KROW + k0 + gsl8;
    const short* bRb1 = B + (size_t)(n0 + br + 160) * KROW + k0 + gsl8;
    const int lA0a = tid * 8,                 lA0b = (tid + 1024) * 8;
    const int lA1a = (tid + 512) * 8,         lA1b = (tid + 1536) * 8;
    const int lBaa = (br * 8 + sslot) * 8,    lBab = ((br + 128) * 8 + sslot) * 8;
    const int lBba = ((br + 32) * 8 + sslot) * 8, lBbb = ((br + 160) * 8 + sslot) * 8;

    auto stAh0 = [&](int b, int co) { gl_lds16(aR0 + co, &As[b][lA0a]); gl_lds16(aR2 + co, &As[b][lA0b]); };
    auto stAh1 = [&](int b, int co) { gl_lds16(aR1 + co, &As[b][lA1a]); gl_lds16(aR3 + co, &As[b][lA1b]); };
    auto stBa  = [&](int b, int co) { gl_lds16(bRa0 + co, &Bs[b][lBaa]); gl_lds16(bRa1 + co, &Bs[b][lBab]); };
    auto stBb  = [&](int b, int co) { gl_lds16(bRb0 + co, &Bs[b][lBba]); gl_lds16(bRb1 + co, &Bs[b][lBbb]); };

    const int fr = lane & 15, g4 = lane >> 4, swz = fr & 7;
    const int NK = KCH / 64;
    short8 aF[2][4], bF[2][4];

    // prologue: tile0's four halves + tile1's Ah0 (5 halves, 10 loads in flight)
    stAh0(0, 0); stBa(0, 0); stBb(0, 0); stAh1(0, 0);
    if (NK > 1) stAh0(1, 64);
    asm volatile("s_waitcnt vmcnt(6)" ::: "memory");   // Ah0_0, Ba_0 landed
    SBAR0;
    __builtin_amdgcn_s_barrier();

    for (int t = 0; t < NK; ++t) {
        const int cur = t & 1, nxt = cur ^ 1;
        const short* Ab = As[cur];
        const short* Bb2 = Bs[cur];
        const int co1 = (t + 1) * 64, co2 = (t + 2) * 64;
        const bool pf1 = (t + 1 < NK), pf2 = (t + 2 < NK);

        // ---------- phase 1: read Ah0 + B n0,n1; stage Ba_{t+1} ----------
#pragma unroll
        for (int ks = 0; ks < 2; ++ks) {
#pragma unroll
            for (int m = 0; m < 4; ++m)
                aF[ks][m] = *(const short8*)&Ab[((wr * 128 + m * 16 + fr) * 8 + ((ks * 4 + g4) ^ swz)) * 8];
#pragma unroll
            for (int n = 0; n < 2; ++n)
                bF[ks][n] = *(const short8*)&Bb2[((wc * 64 + n * 16 + fr) * 8 + ((ks * 4 + g4) ^ swz)) * 8];
        }
        if (pf1) {
            stBa(nxt, co1);
            asm volatile("s_waitcnt vmcnt(6)" ::: "memory");   // Bb_t landed
        } else {
            asm volatile("s_waitcnt vmcnt(2)" ::: "memory");   // tail: [Bb_t,Ah1_t] -> ensure Bb_t
        }
        SBAR0;
        __builtin_amdgcn_s_barrier();
        asm volatile("s_waitcnt lgkmcnt(0)" ::: "memory");
        SBAR0;
        __builtin_amdgcn_s_setprio(1);
#pragma unroll
        for (int ks = 0; ks < 2; ++ks)
#pragma unroll
            for (int m = 0; m < 4; ++m)
#pragma unroll
                for (int n = 0; n < 2; ++n)
                    acc[m][n] = MFMA_BF16(aF[ks][m], bF[ks][n], acc[m][n], 0, 0, 0);
        __builtin_amdgcn_s_setprio(0);

        // ---------- phase 2: read B n2,n3; stage Bb_{t+1} ----------
#pragma unroll
        for (int ks = 0; ks < 2; ++ks)
#pragma unroll
            for (int n = 2; n < 4; ++n)
                bF[ks][n] = *(const short8*)&Bb2[((wc * 64 + n * 16 + fr) * 8 + ((ks * 4 + g4) ^ swz)) * 8];
        if (pf1) {
            stBb(nxt, co1);
            asm volatile("s_waitcnt vmcnt(6)" ::: "memory");   // Ah1_t landed
        } else {
            asm volatile("s_waitcnt vmcnt(0)" ::: "memory");   // tail: ensure Ah1_t
        }
        SBAR0;
        __builtin_amdgcn_s_barrier();
        asm volatile("s_waitcnt lgkmcnt(0)" ::: "memory");
        SBAR0;
        __builtin_amdgcn_s_setprio(1);
#pragma unroll
        for (int ks = 0; ks < 2; ++ks)
#pragma unroll
            for (int m = 0; m < 4; ++m)
#pragma unroll
                for (int n = 2; n < 4; ++n)
                    acc[m][n] = MFMA_BF16(aF[ks][m], bF[ks][n], acc[m][n], 0, 0, 0);
        __builtin_amdgcn_s_setprio(0);

        // ---------- phase 3: read Ah1; stage Ah1_{t+1}; no wait (p4 reads nothing) ----------
#pragma unroll
        for (int ks = 0; ks < 2; ++ks)
#pragma unroll
            for (int m = 0; m < 4; ++m)
                aF[ks][m] = *(const short8*)&Ab[((wr * 128 + 64 + m * 16 + fr) * 8 + ((ks * 4 + g4) ^ swz)) * 8];
        if (pf1) stAh1(nxt, co1);
        __builtin_amdgcn_s_barrier();
        asm volatile("s_waitcnt lgkmcnt(0)" ::: "memory");
        SBAR0;
        __builtin_amdgcn_s_setprio(1);
#pragma unroll
        for (int ks = 0; ks < 2; ++ks)
#pragma unroll
            for (int m = 0; m < 4; ++m)
#pragma unroll
                for (int n = 0; n < 2; ++n)
                    acc[4 + m][n] = MFMA_BF16(aF[ks][m], bF[ks][n], acc[4 + m][n], 0, 0, 0);
        __builtin_amdgcn_s_setprio(0);

        // ---------- phase 4: no reads; stage Ah0_{t+2} into buf[cur] ----------
        if (pf2) {
            stAh0(cur, co2);
            asm volatile("s_waitcnt vmcnt(6)" ::: "memory");   // Ah0_{t+1}, Ba_{t+1} landed
        } else if (pf1) {
            asm volatile("s_waitcnt vmcnt(4)" ::: "memory");   // NK-2: same guarantee, no new issue
        }
        SBAR0;
        __builtin_amdgcn_s_barrier();
        __builtin_amdgcn_s_setprio(1);
#pragma unroll
        for (int ks = 0; ks < 2; ++ks)
#pragma unroll
            for (int m = 0; m < 4; ++m)
#pragma unroll
                for (int n = 2; n < 4; ++n)
                    acc[4 + m][n] = MFMA_BF16(aF[ks][m], bF[ks][n], acc[4 + m][n], 0, 0, 0);
        __builtin_amdgcn_s_setprio(0);
    }
}

// ---------------- GEMM1: H = gelu(Xg @ W1[e]^T + b1[e]) ----------------
#define G1_NX (FF / 256)                 // 16
#define G1_NWG (G1_NX * MB_MAX * NE)     // 4096
__global__ __launch_bounds__(512, 2) void gemm1_k(const short* __restrict__ xb,
                                                  const short* __restrict__ W1b,
                                                  const float* __restrict__ b1,
                                                  const int* __restrict__ cnt,
                                                  const int* __restrict__ offs,
                                                  const int* __restrict__ ptok,
                                                  short* __restrict__ H) {
    __shared__ __align__(16) short As[2][16384];
    __shared__ __align__(16) short Bs[2][16384];
    int wg = (blockIdx.x % 8) * (G1_NWG / 8) + blockIdx.x / 8;   // bijective XCD swizzle
    const int n0 = (wg % G1_NX) * 256;  wg /= G1_NX;
    const int m0 = (wg % MB_MAX) * 256; wg /= MB_MAX;
    const int e = wg;
    const int cnt_e = cnt[e], offs_e = offs[e];
    if (m0 >= cnt_e) return;

    f32x4 acc[8][4];
    gemm8p<DIM, DIM, true>(xb, ptok, W1b + (size_t)e * FF * DIM, offs_e, cnt_e, m0, n0, 0, acc, As, Bs);

    const int lane = threadIdx.x & 63, wave = threadIdx.x >> 6;
    const int wr = wave >> 2, wc = wave & 3;
    const int colb = lane & 15, rowb = (lane >> 4) * 4;
    float b1v[4];
#pragma unroll
    for (int n = 0; n < 4; ++n) b1v[n] = b1[e * FF + n0 + wc * 64 + n * 16 + colb];
#pragma unroll
    for (int m = 0; m < 8; ++m) {
#pragma unroll
        for (int r = 0; r < 4; ++r) {
            const int gm = m0 + wr * 128 + m * 16 + rowb + r;
            if (gm >= cnt_e) continue;
#pragma unroll
            for (int n = 0; n < 4; ++n) {
                const int col = n0 + wc * 64 + n * 16 + colb;
                float v = acc[m][n][r] + b1v[n];
                v = 0.5f * v * (1.f + erff(v * 0.70710678118f));
                H[(size_t)(offs_e + gm) * FF + col] = bf16_of(v);
            }
        }
    }
}

// ------------- GEMM2: ypart = H[:, kslice] @ W2[e][:, kslice]^T  (b2 in combine) -------------
#define G2_NX (DIM / 256)                // 4
template <int KCH>
__global__ __launch_bounds__(512, 2) void gemm2_k(const short* __restrict__ H,
                                                  const short* __restrict__ W2b,
                                                  const int* __restrict__ cnt,
                                                  const int* __restrict__ offs,
                                                  float* __restrict__ y0,
                                                  float* __restrict__ y1,
                                                  int nwg) {
    __shared__ __align__(16) short As[2][16384];
    __shared__ __align__(16) short Bs[2][16384];
    const int KS = FF / KCH;
    int wg = (blockIdx.x % 8) * (nwg / 8) + blockIdx.x / 8;
    int nk = wg % (G2_NX * KS); wg /= (G2_NX * KS);
    const int n0 = (nk % G2_NX) * 256;
    const int kslice = nk / G2_NX;
    const int m0 = (wg % MB_MAX) * 256; wg /= MB_MAX;
    const int e = wg;
    const int cnt_e = cnt[e], offs_e = offs[e];
    if (m0 >= cnt_e) return;

    f32x4 acc[8][4];
    gemm8p<FF, KCH, false>(H, nullptr, W2b + (size_t)e * DIM * FF, offs_e, cnt_e, m0, n0,
                           kslice * KCH, acc, As, Bs);

    float* y = kslice ? y1 : y0;
    const int lane = threadIdx.x & 63, wave = threadIdx.x >> 6;
    const int wr = wave >> 2, wc = wave & 3;
    const int colb = lane & 15, rowb = (lane >> 4) * 4;
#pragma unroll
    for (int m = 0; m < 8; ++m) {
#pragma unroll
        for (int r = 0; r < 4; ++r) {
            const int gm = m0 + wr * 128 + m * 16 + rowb + r;
            if (gm >= cnt_e) continue;
#pragma unroll
            for (int n = 0; n < 4; ++n) {
                const int col = n0 + wc * 64 + n * 16 + colb;
                y[(size_t)(offs_e + gm) * DIM + col] = acc[m][n][r];
            }
        }
    }
}

// -------- combine: out[t] = w1*(ysum(s1)+b2[e1]) + w2*(ysum(s2)+b2[e2]) --------
__global__ __launch_bounds__(256) void combine_k(const float* __restrict__ y0,
                                                 const float* __restrict__ y1,
                                                 int ks,
                                                 const int* __restrict__ slot_of,
                                                 const int* __restrict__ a_exp,
                                                 const float* __restrict__ a_w,
                                                 const float* __restrict__ b2,
                                                 float* __restrict__ out) {
    const int t = blockIdx.x;
    const int c = threadIdx.x;
    const int s1 = slot_of[2 * t], s2 = slot_of[2 * t + 1];
    const int e1 = a_exp[2 * t], e2 = a_exp[2 * t + 1];
    const float w1 = a_w[2 * t], w2 = a_w[2 * t + 1];
    float4 v1 = ((const float4*)(y0 + (size_t)s1 * DIM))[c];
    float4 v2 = ((const float4*)(y0 + (size_t)s2 * DIM))[c];
    if (ks == 2) {
        float4 u1 = ((const float4*)(y1 + (size_t)s1 * DIM))[c];
        float4 u2 = ((const float4*)(y1 + (size_t)s2 * DIM))[c];
        v1.x += u1.x; v1.y += u1.y; v1.z += u1.z; v1.w += u1.w;
        v2.x += u2.x; v2.y += u2.y; v2.z += u2.z; v2.w += u2.w;
    }
    float4 g1 = ((const float4*)(b2 + (size_t)e1 * DIM))[c];
    float4 g2 = ((const float4*)(b2 + (size_t)e2 * DIM))[c];
    float4 o;
    o.x = w1 * (v1.x + g1.x) + w2 * (v2.x + g2.x);
    o.y = w1 * (v1.y + g1.y) + w2 * (v2.y + g2.y);
    o.z = w1 * (v1.z + g1.z) + w2 * (v2.z + g2.z);
    o.w = w1 * (v1.w + g1.w) + w2 * (v2.w + g2.w);
    ((float4*)(out + (size_t)t * DIM))[c] = o;
}

// ---------------- launch ----------------
extern "C" void kernel_launch(void* const* d_in, const int* in_sizes, int n_in,
                              void* d_out, int out_size, void* d_ws, size_t ws_size,
                              hipStream_t stream) {
    const float* x  = (const float*)d_in[0];
    const float* Wr = (const float*)d_in[1];
    const float* W1 = (const float*)d_in[2];
    const float* b1 = (const float*)d_in[3];
    const float* W2 = (const float*)d_in[4];
    const float* b2 = (const float*)d_in[5];
    float* out = (float*)d_out;

    char* w = (char*)d_ws;
    int*   cnt     = (int*)w;
    int*   offs    = (int*)(w + 64);
    int*   a_exp   = (int*)(w + 128);
    int*   a_pos   = a_exp + NASSIGN;
    int*   ptok    = a_pos + NASSIGN;
    int*   slot_of = ptok + NASSIGN;
    float* a_w     = (float*)(slot_of + NASSIGN);
    float* pw      = a_w + NASSIGN;
    char*  p       = (char*)(pw + NASSIGN);
    p = (char*)(((uintptr_t)p + 255) & ~(uintptr_t)255);
    short* xb  = (short*)p;                p += (size_t)NTOK * DIM * 2;
    short* W1b = (short*)p;                p += (size_t)NE * FF * DIM * 2;
    short* W2b = (short*)p;                p += (size_t)NE * DIM * FF * 2;
    short* H   = (short*)p;                p += (size_t)NASSIGN * FF * 2;   // 134 MB
    // y0 aliases W1b (dead after gemm1); NASSIGN*DIM*4 == NE*FF*DIM*2
    float* y0  = (float*)W1b;
    float* y1  = (float*)p;                p += (size_t)NASSIGN * DIM * 4;  // 67 MB (split-K partial)
    const int ks = ((size_t)(p - w) <= ws_size) ? 2 : 1;

    hipMemsetAsync(cnt, 0, 32, stream);

    cvt_k<<<(NE * FF * DIM / 8 + 255) / 256, 256, 0, stream>>>(W1, W1b, NE * FF * DIM / 8);
    cvt_k<<<(NE * DIM * FF / 8 + 255) / 256, 256, 0, stream>>>(W2, W2b, NE * DIM * FF / 8);

    router_k<<<NTOK, 64, 0, stream>>>(x, Wr, cnt, a_exp, a_pos, a_w, xb);
    offsets_k<<<1, 64, 0, stream>>>(cnt, offs);
    scatter_k<<<NASSIGN / 256, 256, 0, stream>>>(a_exp, a_pos, a_w, offs, ptok, pw, slot_of);

    gemm1_k<<<G1_NWG, 512, 0, stream>>>(xb, W1b, b1, cnt, offs, ptok, H);

    if (ks == 2) {
        const int nwg2 = G2_NX * 2 * MB_MAX * NE;   // 2048
        gemm2_k<FF / 2><<<nwg2, 512, 0, stream>>>(H, W2b, cnt, offs, y0, y1, nwg2);
    } else {
        const int nwg2 = G2_NX * MB_MAX * NE;       // 1024
        gemm2_k<FF><<<nwg2, 512, 0, stream>>>(H, W2b, cnt, offs, y0, y1, nwg2);
    }
    combine_k<<<NTOK, 256, 0, stream>>>(y0, y1, ks, slot_of, a_exp, a_w, b2, out);
}

// Round 9
// 692.629 us; speedup vs baseline: 1.3033x; 1.0037x over previous
//
#include <hip/hip_runtime.h>
#include <hip/hip_bf16.h>
#include <math.h>
#include <stdint.h>

#define DIM 1024
#define FF 4096
#define NE 8
#define NTOK 8192
#define NASSIGN (NTOK * 2)
#define MB_MAX (NTOK / 256)     // 32 max m-blocks per expert

typedef short short8 __attribute__((ext_vector_type(8)));
typedef float f32x4 __attribute__((ext_vector_type(4)));

static __device__ __forceinline__ short bf16_of(float f) {
    union { float f; unsigned u; } v; v.f = f;
    unsigned r = v.u + 0x7fffu + ((v.u >> 16) & 1u);   // RNE
    return (short)(r >> 16);
}

static __device__ __forceinline__ short8 cvt8(float4 a, float4 b) {
    short8 r;
    r[0] = bf16_of(a.x); r[1] = bf16_of(a.y); r[2] = bf16_of(a.z); r[3] = bf16_of(a.w);
    r[4] = bf16_of(b.x); r[5] = bf16_of(b.y); r[6] = bf16_of(b.z); r[7] = bf16_of(b.w);
    return r;
}

static __device__ __forceinline__ void gl_lds16(const short* g, short* lds) {
    __builtin_amdgcn_global_load_lds(
        (const __attribute__((address_space(1))) void*)g,
        (__attribute__((address_space(3))) void*)lds, 16, 0, 0);
}

// fast exact-form gelu: Abramowitz-Stegun 7.1.26 erf approx, |err| < 1.5e-7
static __device__ __forceinline__ float gelu_f(float x) {
    float z = x * 0.70710678118f;
    float az = fabsf(z);
    float t = __builtin_amdgcn_rcpf(1.f + 0.3275911f * az);
    float poly = t * (0.254829592f + t * (-0.284496736f + t * (1.421413741f +
                 t * (-1.453152027f + t * 1.061405429f))));
    float e = __expf(-z * z);
    float erfv = 1.f - poly * e;
    erfv = (z < 0.f) ? -erfv : erfv;
    return 0.5f * x * (1.f + erfv);
}

// ---------------- f32 -> bf16 bulk convert ----------------
__global__ __launch_bounds__(256) void cvt_k(const float* __restrict__ in,
                                             short* __restrict__ out, int n8) {
    int i = blockIdx.x * blockDim.x + threadIdx.x;
    if (i >= n8) return;
    float4 a = ((const float4*)in)[2 * i];
    float4 b = ((const float4*)in)[2 * i + 1];
    ((short8*)out)[i] = cvt8(a, b);
}

// ---------------- router (fused: also emits xb = bf16(x)) ----------------
__global__ void router_k(const float* __restrict__ x, const float* __restrict__ Wr,
                         int* __restrict__ cnt, int* __restrict__ a_exp,
                         int* __restrict__ a_pos, float* __restrict__ a_w,
                         short* __restrict__ xb) {
    int t = blockIdx.x;
    int lane = threadIdx.x;
    const float* xr = x + (size_t)t * DIM;
    short* xbr = xb + (size_t)t * DIM;
    float p[NE];
#pragma unroll
    for (int e = 0; e < NE; ++e) p[e] = 0.f;
    for (int i = 0; i < DIM / 64; ++i) {
        float xv = xr[lane + i * 64];
        xbr[lane + i * 64] = bf16_of(xv);
#pragma unroll
        for (int e = 0; e < NE; ++e) p[e] += xv * Wr[e * DIM + lane + i * 64];
    }
#pragma unroll
    for (int off = 32; off >= 1; off >>= 1)
#pragma unroll
        for (int e = 0; e < NE; ++e) p[e] += __shfl_xor(p[e], off);
    if (lane == 0) {
        float mx = p[0];
#pragma unroll
        for (int e = 1; e < NE; ++e) mx = fmaxf(mx, p[e]);
        float pr[NE]; float s = 0.f;
#pragma unroll
        for (int e = 0; e < NE; ++e) { pr[e] = expf(p[e] - mx); s += pr[e]; }
#pragma unroll
        for (int e = 0; e < NE; ++e) pr[e] /= s;
        int i1 = 0;
#pragma unroll
        for (int e = 1; e < NE; ++e) if (pr[e] > pr[i1]) i1 = e;
        int i2 = (i1 == 0) ? 1 : 0;
#pragma unroll
        for (int e = 0; e < NE; ++e) if (e != i1 && pr[e] > pr[i2]) i2 = e;
        float w1 = pr[i1], w2 = pr[i2], nrm = w1 + w2;
        w1 /= nrm; w2 /= nrm;
        int p1 = atomicAdd(&cnt[i1], 1);
        int p2 = atomicAdd(&cnt[i2], 1);
        a_exp[2 * t] = i1;     a_pos[2 * t] = p1;     a_w[2 * t] = w1;
        a_exp[2 * t + 1] = i2; a_pos[2 * t + 1] = p2; a_w[2 * t + 1] = w2;
    }
}

__global__ void offsets_k(const int* __restrict__ cnt, int* __restrict__ offs) {
    if (threadIdx.x == 0) {
        int s = 0;
        for (int e = 0; e < NE; ++e) { offs[e] = s; s += cnt[e]; }
        offs[NE] = s;
    }
}

__global__ void scatter_k(const int* __restrict__ a_exp, const int* __restrict__ a_pos,
                          const float* __restrict__ a_w, const int* __restrict__ offs,
                          int* __restrict__ ptok, float* __restrict__ pw,
                          int* __restrict__ slot_of) {
    int a = blockIdx.x * blockDim.x + threadIdx.x;
    if (a >= NASSIGN) return;
    int e = a_exp[a];
    int r = offs[e] + a_pos[a];
    ptok[r] = a >> 1;
    pw[r] = a_w[a];
    slot_of[a] = r;
}

// ======== 256x256 grouped GEMM core — rotated read-ahead, 1 vmcnt/K-tile ========
// LDS: 2 K-tile buffers (A 256x64 + B 256x64 bf16) = 128 KB. 8 waves (2M x 4N).
// Swizzle: LDS[row][slot] = global[row][slot ^ (row&7)]  -> 0 bank conflicts (verified r7/8).
// READ-AHEAD: phase p's ds_reads fetch phase p+1's frags; lgkm(0) at p+1 entry waits on
// reads a full phase old (~free). Frag regs (static names, no ping-pong hazards):
//   aF0 (Ah0_t): read @p4(t-1), used p1,p2, rewritten @p4(t)
//   bF01 (Bn01_t): read @p4(t-1), used p1,p3, rewritten @p4(t)
//   bF23 (Bn23_t): read @p1(t),   used p2,p4, rewritten @p1(t+1)
//   aF1 (Ah1_t):  read @p2(t),   used p3,p4, rewritten @p2(t+1)
// STAGES: Bb_{t+1}@p1, Ah1_{t+1}@p2, Ah0_{t+2}@p3(cur), Ba_{t+2}@p4(cur).
// SINGLE WAIT vmcnt(4) @p4(t): FIFO = [Ah0_{t+1}(p3,t-1), Ba_{t+1}(p4,t-1), Bb_{t+1}(p1,t),
//   Ah1_{t+1}(p2,t), Ah0_{t+2}(p3,t), Ba_{t+2}(p4,t)] -> drains tile t+1 fully, leaves the
//   2 newest halves in flight. Oldest waited load is 5 phases old. Tail: vmcnt(0) @p4(NK-2).
// LDS write hazards (stage vs frag reads of the SAME region, all sealed by >=1 barrier):
//   p3 stage cur-Ah0: Ah0_t read @p4(t-1) < p4(t-1) bar.  p4 stage cur-Ba: read @p4(t-1).
//   p1/p2 stage nxt-Bb/Ah1: read @p1/p2(t-1) < their barriers. All disjoint regions.
#define MFMA_BF16 __builtin_amdgcn_mfma_f32_16x16x32_bf16
#define SBAR0 __builtin_amdgcn_sched_barrier(0)
#define LGKM0 asm volatile("s_waitcnt lgkmcnt(0)" ::: "memory")

template <int KROW, int KCH, bool GATHER>
__device__ __forceinline__ void gemm8p(const short* __restrict__ A,
                                       const int* __restrict__ ptok,
                                       const short* __restrict__ B,
                                       int offs_e, int cnt_e, int m0, int n0, int k0,
                                       f32x4 acc[8][4],
                                       short (*As)[16384], short (*Bs)[16384]) {
    const int tid = threadIdx.x;
    const int lane = tid & 63, wave = tid >> 6;
    const int wr = wave >> 2, wc = wave & 3;

#pragma unroll
    for (int m = 0; m < 8; ++m)
#pragma unroll
        for (int n = 0; n < 4; ++n) acc[m][n] = (f32x4){0.f, 0.f, 0.f, 0.f};

    const int srow = tid >> 3, sslot = tid & 7;
    const int gsl8 = (sslot ^ (srow & 7)) * 8;      // inverse-swizzled global 16B slot

    int ra0 = m0 + srow;       if (ra0 >= cnt_e) ra0 = cnt_e - 1;   // Ah0
    int ra2 = m0 + srow + 128; if (ra2 >= cnt_e) ra2 = cnt_e - 1;   // Ah0
    int ra1 = m0 + srow + 64;  if (ra1 >= cnt_e) ra1 = cnt_e - 1;   // Ah1
    int ra3 = m0 + srow + 192; if (ra3 >= cnt_e) ra3 = cnt_e - 1;   // Ah1
    const short* aR0 = A + (GATHER ? (size_t)ptok[offs_e + ra0] : (size_t)(offs_e + ra0)) * KROW + k0 + gsl8;
    const short* aR2 = A + (GATHER ? (size_t)ptok[offs_e + ra2] : (size_t)(offs_e + ra2)) * KROW + k0 + gsl8;
    const short* aR1 = A + (GATHER ? (size_t)ptok[offs_e + ra1] : (size_t)(offs_e + ra1)) * KROW + k0 + gsl8;
    const short* aR3 = A + (GATHER ? (size_t)ptok[offs_e + ra3] : (size_t)(offs_e + ra3)) * KROW + k0 + gsl8;
    const int br = (srow & 31) + (srow >> 5) * 64;
    const short* bRa0 = B + (size_t)(n0 + br) * KROW + k0 + gsl8;
    const short* bRa1 = B + (size_t)(n0 + br + 128) * KROW + k0 + gsl8;
    const short* bRb0 = B + (size_t)(n0 + br + 32) * KROW + k0 + gsl8;
    const short* bRb1 = B + (size_t)(n0 + br + 160) * KROW + k0 + gsl8;
    const int lA0a = tid * 8,                 lA0b = (tid + 1024) * 8;
    const int lA1a = (tid + 512) * 8,         lA1b = (tid + 1536) * 8;
    const int lBaa = (br * 8 + sslot) * 8,    lBab = ((br + 128) * 8 + sslot) * 8;
    const int lBba = ((br + 32) * 8 + sslot) * 8, lBbb = ((br + 160) * 8 + sslot) * 8;

    auto stAh0 = [&](int b, int co) { gl_lds16(aR0 + co, &As[b][lA0a]); gl_lds16(aR2 + co, &As[b][lA0b]); };
    auto stAh1 = [&](int b, int co) { gl_lds16(aR1 + co, &As[b][lA1a]); gl_lds16(aR3 + co, &As[b][lA1b]); };
    auto stBa  = [&](int b, int co) { gl_lds16(bRa0 + co, &Bs[b][lBaa]); gl_lds16(bRa1 + co, &Bs[b][lBab]); };
    auto stBb  = [&](int b, int co) { gl_lds16(bRb0 + co, &Bs[b][lBba]); gl_lds16(bRb1 + co, &Bs[b][lBbb]); };

    const int fr = lane & 15, g4 = lane >> 4, swz = fr & 7;
    const int NK = KCH / 64;

    short8 aF0[2][4], aF1[2][4], bF01[2][2], bF23[2][2];

    auto rdA0 = [&](const short* P) {
#pragma unroll
        for (int ks = 0; ks < 2; ++ks)
#pragma unroll
            for (int m = 0; m < 4; ++m)
                aF0[ks][m] = *(const short8*)&P[((wr * 128 + m * 16 + fr) * 8 + ((ks * 4 + g4) ^ swz)) * 8];
    };
    auto rdA1 = [&](const short* P) {
#pragma unroll
        for (int ks = 0; ks < 2; ++ks)
#pragma unroll
            for (int m = 0; m < 4; ++m)
                aF1[ks][m] = *(const short8*)&P[((wr * 128 + 64 + m * 16 + fr) * 8 + ((ks * 4 + g4) ^ swz)) * 8];
    };
    auto rdB01 = [&](const short* P) {
#pragma unroll
        for (int ks = 0; ks < 2; ++ks)
#pragma unroll
            for (int n = 0; n < 2; ++n)
                bF01[ks][n] = *(const short8*)&P[((wc * 64 + n * 16 + fr) * 8 + ((ks * 4 + g4) ^ swz)) * 8];
    };
    auto rdB23 = [&](const short* P) {
#pragma unroll
        for (int ks = 0; ks < 2; ++ks)
#pragma unroll
            for (int n = 0; n < 2; ++n)
                bF23[ks][n] = *(const short8*)&P[((wc * 64 + (n + 2) * 16 + fr) * 8 + ((ks * 4 + g4) ^ swz)) * 8];
    };

    // prologue: tile0 (4 halves) + tile1's Ah0,Ba; vmcnt(4) covers tile0 entirely
    stAh0(0, 0); stBa(0, 0); stBb(0, 0); stAh1(0, 0);
    if (NK > 1) {
        stAh0(1, 64); stBa(1, 64);
        asm volatile("s_waitcnt vmcnt(4)" ::: "memory");
    } else {
        asm volatile("s_waitcnt vmcnt(0)" ::: "memory");
    }
    SBAR0;
    __builtin_amdgcn_s_barrier();
    rdA0(As[0]); rdB01(Bs[0]);      // tile0 p1 frags (drained by p1's LGKM0)

    for (int t = 0; t < NK; ++t) {
        const int cur = t & 1, nxt = cur ^ 1;
        const short* Ab = As[cur];
        const short* Bb2 = Bs[cur];
        const int co1 = (t + 1) * 64, co2 = (t + 2) * 64;
        const bool pf1 = (t + 1 < NK), pf2 = (t + 2 < NK);

        // ---- P1: MFMA mh0 x n01; read Bn23_t; stage Bb_{t+1} ----
        LGKM0; SBAR0;
        __builtin_amdgcn_s_setprio(1);
#pragma unroll
        for (int ks = 0; ks < 2; ++ks)
#pragma unroll
            for (int m = 0; m < 4; ++m)
#pragma unroll
                for (int n = 0; n < 2; ++n)
                    acc[m][n] = MFMA_BF16(aF0[ks][m], bF01[ks][n], acc[m][n], 0, 0, 0);
        __builtin_amdgcn_s_setprio(0);
        rdB23(Bb2);
        if (pf1) stBb(nxt, co1);
        SBAR0;
        __builtin_amdgcn_s_barrier();

        // ---- P2: MFMA mh0 x n23; read Ah1_t; stage Ah1_{t+1} ----
        LGKM0; SBAR0;
        __builtin_amdgcn_s_setprio(1);
#pragma unroll
        for (int ks = 0; ks < 2; ++ks)
#pragma unroll
            for (int m = 0; m < 4; ++m)
#pragma unroll
                for (int n = 0; n < 2; ++n)
                    acc[m][n + 2] = MFMA_BF16(aF0[ks][m], bF23[ks][n], acc[m][n + 2], 0, 0, 0);
        __builtin_amdgcn_s_setprio(0);
        rdA1(Ab);
        if (pf1) stAh1(nxt, co1);
        SBAR0;
        __builtin_amdgcn_s_barrier();

        // ---- P3: MFMA mh1 x n01; stage Ah0_{t+2} (into cur) ----
        LGKM0; SBAR0;
        __builtin_amdgcn_s_setprio(1);
#pragma unroll
        for (int ks = 0; ks < 2; ++ks)
#pragma unroll
            for (int m = 0; m < 4; ++m)
#pragma unroll
                for (int n = 0; n < 2; ++n)
                    acc[4 + m][n] = MFMA_BF16(aF1[ks][m], bF01[ks][n], acc[4 + m][n], 0, 0, 0);
        __builtin_amdgcn_s_setprio(0);
        if (pf2) stAh0(cur, co2);
        SBAR0;
        __builtin_amdgcn_s_barrier();

        // ---- P4: MFMA mh1 x n23; stage Ba_{t+2}; SINGLE vmcnt; read tile t+1 p1 frags ----
        __builtin_amdgcn_s_setprio(1);
#pragma unroll
        for (int ks = 0; ks < 2; ++ks)
#pragma unroll
            for (int m = 0; m < 4; ++m)
#pragma unroll
                for (int n = 0; n < 2; ++n)
                    acc[4 + m][n + 2] = MFMA_BF16(aF1[ks][m], bF23[ks][n], acc[4 + m][n + 2], 0, 0, 0);
        __builtin_amdgcn_s_setprio(0);
        if (pf2) {
            stBa(cur, co2);
            asm volatile("s_waitcnt vmcnt(4)" ::: "memory");
        } else if (pf1) {
            asm volatile("s_waitcnt vmcnt(0)" ::: "memory");
        }
        SBAR0;
        if (pf1) { rdA0(As[nxt]); rdB01(Bs[nxt]); }
        SBAR0;
        __builtin_amdgcn_s_barrier();
    }
}

// ---------------- GEMM1: H = gelu(Xg @ W1[e]^T + b1[e]) ----------------
#define G1_NX (FF / 256)                 // 16
#define G1_NWG (G1_NX * MB_MAX * NE)     // 4096
__global__ __launch_bounds__(512, 2) void gemm1_k(const short* __restrict__ xb,
                                                  const short* __restrict__ W1b,
                                                  const float* __restrict__ b1,
                                                  const int* __restrict__ cnt,
                                                  const int* __restrict__ offs,
                                                  const int* __restrict__ ptok,
                                                  short* __restrict__ H) {
    __shared__ __align__(16) short As[2][16384];
    __shared__ __align__(16) short Bs[2][16384];
    int wg = (blockIdx.x % 8) * (G1_NWG / 8) + blockIdx.x / 8;   // bijective XCD swizzle
    const int n0 = (wg % G1_NX) * 256;  wg /= G1_NX;
    const int m0 = (wg % MB_MAX) * 256; wg /= MB_MAX;
    const int e = wg;
    const int cnt_e = cnt[e], offs_e = offs[e];
    if (m0 >= cnt_e) return;

    f32x4 acc[8][4];
    gemm8p<DIM, DIM, true>(xb, ptok, W1b + (size_t)e * FF * DIM, offs_e, cnt_e, m0, n0, 0, acc, As, Bs);

    const int lane = threadIdx.x & 63, wave = threadIdx.x >> 6;
    const int wr = wave >> 2, wc = wave & 3;
    const int colb = lane & 15, rowb = (lane >> 4) * 4;
    float b1v[4];
#pragma unroll
    for (int n = 0; n < 4; ++n) b1v[n] = b1[e * FF + n0 + wc * 64 + n * 16 + colb];
#pragma unroll
    for (int m = 0; m < 8; ++m) {
#pragma unroll
        for (int r = 0; r < 4; ++r) {
            const int gm = m0 + wr * 128 + m * 16 + rowb + r;
            if (gm >= cnt_e) continue;
#pragma unroll
            for (int n = 0; n < 4; ++n) {
                const int col = n0 + wc * 64 + n * 16 + colb;
                float v = gelu_f(acc[m][n][r] + b1v[n]);
                H[(size_t)(offs_e + gm) * FF + col] = bf16_of(v);
            }
        }
    }
}

// ------------- GEMM2: ypart = H[:, kslice] @ W2[e][:, kslice]^T  (b2 in combine) -------------
#define G2_NX (DIM / 256)                // 4
template <int KCH>
__global__ __launch_bounds__(512, 2) void gemm2_k(const short* __restrict__ H,
                                                  const short* __restrict__ W2b,
                                                  const int* __restrict__ cnt,
                                                  const int* __restrict__ offs,
                                                  float* __restrict__ y0,
                                                  float* __restrict__ y1,
                                                  int nwg) {
    __shared__ __align__(16) short As[2][16384];
    __shared__ __align__(16) short Bs[2][16384];
    const int KS = FF / KCH;
    int wg = (blockIdx.x % 8) * (nwg / 8) + blockIdx.x / 8;
    int nk = wg % (G2_NX * KS); wg /= (G2_NX * KS);
    const int n0 = (nk % G2_NX) * 256;
    const int kslice = nk / G2_NX;
    const int m0 = (wg % MB_MAX) * 256; wg /= MB_MAX;
    const int e = wg;
    const int cnt_e = cnt[e], offs_e = offs[e];
    if (m0 >= cnt_e) return;

    f32x4 acc[8][4];
    gemm8p<FF, KCH, false>(H, nullptr, W2b + (size_t)e * DIM * FF, offs_e, cnt_e, m0, n0,
                           kslice * KCH, acc, As, Bs);

    float* y = kslice ? y1 : y0;
    const int lane = threadIdx.x & 63, wave = threadIdx.x >> 6;
    const int wr = wave >> 2, wc = wave & 3;
    const int colb = lane & 15, rowb = (lane >> 4) * 4;
#pragma unroll
    for (int m = 0; m < 8; ++m) {
#pragma unroll
        for (int r = 0; r < 4; ++r) {
            const int gm = m0 + wr * 128 + m * 16 + rowb + r;
            if (gm >= cnt_e) continue;
#pragma unroll
            for (int n = 0; n < 4; ++n) {
                const int col = n0 + wc * 64 + n * 16 + colb;
                y[(size_t)(offs_e + gm) * DIM + col] = acc[m][n][r];
            }
        }
    }
}

// -------- combine: out[t] = w1*(ysum(s1)+b2[e1]) + w2*(ysum(s2)+b2[e2]) --------
__global__ __launch_bounds__(256) void combine_k(const float* __restrict__ y0,
                                                 const float* __restrict__ y1,
                                                 int ks,
                                                 const int* __restrict__ slot_of,
                                                 const int* __restrict__ a_exp,
                                                 const float* __restrict__ a_w,
                                                 const float* __restrict__ b2,
                                                 float* __restrict__ out) {
    const int t = blockIdx.x;
    const int c = threadIdx.x;
    const int s1 = slot_of[2 * t], s2 = slot_of[2 * t + 1];
    const int e1 = a_exp[2 * t], e2 = a_exp[2 * t + 1];
    const float w1 = a_w[2 * t], w2 = a_w[2 * t + 1];
    float4 v1 = ((const float4*)(y0 + (size_t)s1 * DIM))[c];
    float4 v2 = ((const float4*)(y0 + (size_t)s2 * DIM))[c];
    if (ks == 2) {
        float4 u1 = ((const float4*)(y1 + (size_t)s1 * DIM))[c];
        float4 u2 = ((const float4*)(y1 + (size_t)s2 * DIM))[c];
        v1.x += u1.x; v1.y += u1.y; v1.z += u1.z; v1.w += u1.w;
        v2.x += u2.x; v2.y += u2.y; v2.z += u2.z; v2.w += u2.w;
    }
    float4 g1 = ((const float4*)(b2 + (size_t)e1 * DIM))[c];
    float4 g2 = ((const float4*)(b2 + (size_t)e2 * DIM))[c];
    float4 o;
    o.x = w1 * (v1.x + g1.x) + w2 * (v2.x + g2.x);
    o.y = w1 * (v1.y + g1.y) + w2 * (v2.y + g2.y);
    o.z = w1 * (v1.z + g1.z) + w2 * (v2.z + g2.z);
    o.w = w1 * (v1.w + g1.w) + w2 * (v2.w + g2.w);
    ((float4*)(out + (size_t)t * DIM))[c] = o;
}

// ---------------- launch ----------------
extern "C" void kernel_launch(void* const* d_in, const int* in_sizes, int n_in,
                              void* d_out, int out_size, void* d_ws, size_t ws_size,
                              hipStream_t stream) {
    const float* x  = (const float*)d_in[0];
    const float* Wr = (const float*)d_in[1];
    const float* W1 = (const float*)d_in[2];
    const float* b1 = (const float*)d_in[3];
    const float* W2 = (const float*)d_in[4];
    const float* b2 = (const float*)d_in[5];
    float* out = (float*)d_out;

    char* w = (char*)d_ws;
    int*   cnt     = (int*)w;
    int*   offs    = (int*)(w + 64);
    int*   a_exp   = (int*)(w + 128);
    int*   a_pos   = a_exp + NASSIGN;
    int*   ptok    = a_pos + NASSIGN;
    int*   slot_of = ptok + NASSIGN;
    float* a_w     = (float*)(slot_of + NASSIGN);
    float* pw      = a_w + NASSIGN;
    char*  p       = (char*)(pw + NASSIGN);
    p = (char*)(((uintptr_t)p + 255) & ~(uintptr_t)255);
    short* xb  = (short*)p;                p += (size_t)NTOK * DIM * 2;
    short* W1b = (short*)p;                p += (size_t)NE * FF * DIM * 2;
    short* W2b = (short*)p;                p += (size_t)NE * DIM * FF * 2;
    short* H   = (short*)p;                p += (size_t)NASSIGN * FF * 2;   // 134 MB
    // y0 aliases W1b (dead after gemm1); NASSIGN*DIM*4 == NE*FF*DIM*2
    float* y0  = (float*)W1b;
    float* y1  = (float*)p;                p += (size_t)NASSIGN * DIM * 4;  // 67 MB (split-K partial)
    const int ks = ((size_t)(p - w) <= ws_size) ? 2 : 1;

    hipMemsetAsync(cnt, 0, 32, stream);

    cvt_k<<<(NE * FF * DIM / 8 + 255) / 256, 256, 0, stream>>>(W1, W1b, NE * FF * DIM / 8);
    cvt_k<<<(NE * DIM * FF / 8 + 255) / 256, 256, 0, stream>>>(W2, W2b, NE * DIM * FF / 8);

    router_k<<<NTOK, 64, 0, stream>>>(x, Wr, cnt, a_exp, a_pos, a_w, xb);
    offsets_k<<<1, 64, 0, stream>>>(cnt, offs);
    scatter_k<<<NASSIGN / 256, 256, 0, stream>>>(a_exp, a_pos, a_w, offs, ptok, pw, slot_of);

    gemm1_k<<<G1_NWG, 512, 0, stream>>>(xb, W1b, b1, cnt, offs, ptok, H);

    if (ks == 2) {
        const int nwg2 = G2_NX * 2 * MB_MAX * NE;   // 2048
        gemm2_k<FF / 2><<<nwg2, 512, 0, stream>>>(H, W2b, cnt, offs, y0, y1, nwg2);
    } else {
        const int nwg2 = G2_NX * MB_MAX * NE;       // 1024
        gemm2_k<FF><<<nwg2, 512, 0, stream>>>(H, W2b, cnt, offs, y0, y1, nwg2);
    }
    combine_k<<<NTOK, 256, 0, stream>>>(y0, y1, ks, slot_of, a_exp, a_w, b2, out);
}